// Round 6
// baseline (281.039 us; speedup 1.0000x reference)
//
#include <hip/hip_runtime.h>
#include <hip/hip_bf16.h>
#include <stdint.h>

typedef unsigned short ushort_t;

#define BB 8
#define SS 1024
#define TT 1024
#define DD 1024
#define INF_ 1e10f

__device__ __forceinline__ float b2f(ushort_t u){
  union { unsigned u32; float f; } x; x.u32 = ((unsigned)u) << 16; return x.f;
}
__device__ __forceinline__ ushort_t f2b(float f){
  union { float f; unsigned u; } x; x.f = f;
  unsigned r = x.u + 0x7FFFu + ((x.u >> 16) & 1u);
  return (ushort_t)(r >> 16);
}

// ---- preamble: blocks 0..2047 transpose Wq/Wk -> bf16; 2048..2055 steps;
//      blocks 2056..2063 v2[f] = sum_d Wk[d,f]*bq[d] (atomic-free) ----
__global__ __launch_bounds__(256) void pre_kernel(
    const float* __restrict__ Wq, const float* __restrict__ Wk,
    ushort_t* __restrict__ WqT, ushort_t* __restrict__ WkT,
    const float* __restrict__ msrc, const float* __restrict__ mtrg,
    float* __restrict__ steps, float* __restrict__ v2,
    const float* __restrict__ bq)
{
  __shared__ float tile[32][33];
  __shared__ float sh[8];
  __shared__ float shv[128];
  int blk = blockIdx.x, tid = threadIdx.x;
  if (blk < 2048){
    const float* src = (blk >= 1024) ? Wk : Wq;
    ushort_t* dst = (blk >= 1024) ? WkT : WqT;
    int q = blk & 1023;
    int tx = q & 31, ty = q >> 5;
    int c = tid & 31, r0 = tid >> 5;
    #pragma unroll
    for (int k = 0; k < 4; k++){
      int r = r0 + k*8;
      tile[r][c] = src[(size_t)(ty*32 + r)*DD + tx*32 + c];
    }
    __syncthreads();
    #pragma unroll
    for (int k = 0; k < 4; k++){
      int r = r0 + k*8;
      dst[(size_t)(tx*32 + r)*DD + ty*32 + c] = f2b(tile[c][r]);
    }
  } else if (blk < 2056){
    int b = blk - 2048;
    float a = 0.f, c = 0.f;
    for (int i = tid; i < SS; i += 256) a += msrc[b*SS + i];
    for (int i = tid; i < TT; i += 256) c += mtrg[b*TT + i];
    #pragma unroll
    for (int o = 32; o; o >>= 1){ a += __shfl_xor(a, o); c += __shfl_xor(c, o); }
    int wv = tid >> 6, ln = tid & 63;
    if (!ln){ sh[wv] = a; sh[4+wv] = c; }
    __syncthreads();
    if (!tid){
      float sa = sh[0]+sh[1]+sh[2]+sh[3];
      float sc = sh[4]+sh[5]+sh[6]+sh[7];
      steps[b] = sa / sc;
    }
  } else {
    // v2: 8 blocks x 128 cols; each (col, half) thread sums 512 d's
    int b2 = blk - 2056;                 // 0..7
    int fcol = b2*128 + (tid & 127);
    int half = tid >> 7;                 // 0 or 1
    float a = 0.f;
    const float* Wp = Wk + (size_t)(half*512)*DD + fcol;
    for (int d = 0; d < 512; ++d) a += Wp[(size_t)d*DD] * bq[half*512 + d];
    if (half == 0) shv[tid] = a;
    __syncthreads();
    if (half == 1) v2[fcol] = a + shv[tid & 127];
  }
}

// ------- key rows fp32->bf16 + kw = key·wg, cv = key·v2; blocks >= BB*SS do the
//         WmT split-K reduce (4 fp32 partials -> bf16), fused to save a dispatch -------
__global__ __launch_bounds__(256) void key_convert_kernel(
    const float* __restrict__ key, const float* __restrict__ wg,
    const float* __restrict__ v2f, ushort_t* __restrict__ keyb,
    float* __restrict__ kw, float* __restrict__ cv,
    const float* __restrict__ part, ushort_t* __restrict__ wmt)
{
  __shared__ float sh[8];
  int blk = blockIdx.x;
  if (blk >= BB*SS){
    int i4 = (blk - BB*SS) * 256 + threadIdx.x;   // float4 idx, n = 1024*1024/4
    const float4* p = (const float4*)part;
    float4 a = p[i4];
    float4 b = p[i4 + 262144];
    float4 c = p[i4 + 524288];
    float4 d = p[i4 + 786432];
    ushort4 o;
    o.x = f2b(a.x + b.x + c.x + d.x);
    o.y = f2b(a.y + b.y + c.y + d.y);
    o.z = f2b(a.z + b.z + c.z + d.z);
    o.w = f2b(a.w + b.w + c.w + d.w);
    ((ushort4*)wmt)[i4] = o;
    return;
  }
  int row = blk;              // b*SS + s
  int tid = threadIdx.x, d0 = tid*4;
  float4 v = *(const float4*)(key + (size_t)row*DD + d0);
  ushort4 o; o.x=f2b(v.x); o.y=f2b(v.y); o.z=f2b(v.z); o.w=f2b(v.w);
  *(ushort4*)(keyb + (size_t)row*DD + d0) = o;
  float4 w4 = *(const float4*)(wg + d0);
  float4 u4 = *(const float4*)(v2f + d0);
  float pk = v.x*w4.x + v.y*w4.y + v.z*w4.z + v.w*w4.w;
  float pc = v.x*u4.x + v.y*u4.y + v.z*u4.z + v.w*u4.w;
  #pragma unroll
  for (int off = 32; off; off >>= 1){ pk += __shfl_xor(pk, off); pc += __shfl_xor(pc, off); }
  int wvv = tid >> 6;
  if ((tid & 63) == 0){ sh[wvv] = pk; sh[4+wvv] = pc; }
  __syncthreads();
  if (!tid){
    kw[row] = sh[0]+sh[1]+sh[2]+sh[3];
    cv[row] = sh[4]+sh[5]+sh[6]+sh[7];
  }
}

// ---- m97-style bf16 GEMM (kept for the small WmT = WkT@WqT^T split-K GEMM) ----
typedef __bf16 bf16x8 __attribute__((ext_vector_type(8)));
typedef float f32x4 __attribute__((ext_vector_type(4)));

#define CP16(g, l) __builtin_amdgcn_global_load_lds( \
    (const __attribute__((address_space(1))) void*)(g), \
    (__attribute__((address_space(3))) void*)(l), 16, 0, 0)

__global__ __launch_bounds__(256, 2) void gemm_bt_kernel(
    const ushort_t* __restrict__ A, const ushort_t* __restrict__ Bm,
    const float* __restrict__ bias, void* __restrict__ Cv,
    int M, int N, int K, int lda, int ldb,
    long long sA, long long sB, long long sC, int hasBias, int outBF16,
    int gx, int gxy)
{
  __shared__ ushort_t lA[128*32];
  __shared__ ushort_t lB[128*32];

  const int bpx = gridDim.x >> 3;
  const int lin = blockIdx.x;
  const int glob = (lin & 7) * bpx + (lin >> 3);
  const int bz = glob / gxy;
  const int rem = glob - bz * gxy;
  const int by = rem / gx;
  const int bx = rem - by * gx;

  A  += (size_t)bz * sA;
  Bm += (size_t)bz * sB;

  const int tid = threadIdx.x;
  const int wv = tid >> 6, ln = tid & 63;
  const int r4 = ln >> 2, c8 = (ln & 3) * 8;

  const ushort_t* gA0 = A  + (size_t)(by*128 + wv*32 + r4) * lda + c8;
  const ushort_t* gA1 = gA0 + (size_t)16 * lda;
  const ushort_t* gB0 = Bm + (size_t)(bx*128 + wv*32 + r4) * ldb + c8;
  const ushort_t* gB1 = gB0 + (size_t)16 * ldb;
  ushort_t* lA0 = &lA[(wv*32     ) * 32];
  ushort_t* lA1 = &lA[(wv*32 + 16) * 32];
  ushort_t* lB0 = &lB[(wv*32     ) * 32];
  ushort_t* lB1 = &lB[(wv*32 + 16) * 32];

  const int lm = ln & 15, qd = ln >> 4;
  const int wm = (wv >> 1) * 64, wn = (wv & 1) * 64;

  f32x4 acc[4][4];
  #pragma unroll
  for (int i = 0; i < 4; i++)
    #pragma unroll
    for (int j = 0; j < 4; j++) acc[i][j] = (f32x4){0.f, 0.f, 0.f, 0.f};

  for (int k0 = 0; k0 < K; k0 += 32){
    CP16(gA0, lA0); CP16(gA1, lA1); CP16(gB0, lB0); CP16(gB1, lB1);
    gA0 += 32; gA1 += 32; gB0 += 32; gB1 += 32;
    __syncthreads();
    bf16x8 af[4], bf[4];
    #pragma unroll
    for (int i = 0; i < 4; i++) af[i] = *(const bf16x8*)&lA[(wm + i*16 + lm)*32 + qd*8];
    #pragma unroll
    for (int j = 0; j < 4; j++) bf[j] = *(const bf16x8*)&lB[(wn + j*16 + lm)*32 + qd*8];
    #pragma unroll
    for (int i = 0; i < 4; i++)
      #pragma unroll
      for (int j = 0; j < 4; j++)
        acc[i][j] = __builtin_amdgcn_mfma_f32_16x16x32_bf16(af[i], bf[j], acc[i][j], 0, 0, 0);
    __syncthreads();
  }

  // C/D layout: col = lane&15, row = (lane>>4)*4 + reg   [verified m89/m91]
  const int row0 = by*128 + wm + qd*4;
  const int col0 = bx*128 + wn + lm;
  ushort_t* Cb = (ushort_t*)Cv + (size_t)bz * sC;
  float*    Cf = (float*)Cv    + (size_t)bz * sC;
  #pragma unroll
  for (int j = 0; j < 4; j++){
    int col = col0 + j*16;
    float bv = hasBias ? bias[col] : 0.f;
    #pragma unroll
    for (int i = 0; i < 4; i++)
      #pragma unroll
      for (int r = 0; r < 4; r++){
        size_t idx = (size_t)(row0 + i*16 + r) * N + col;
        float v = acc[i][j][r] + bv;
        if (outBF16) Cb[idx] = f2b(v); else Cf[idx] = v;
      }
  }
}

// ==================== 256x128-tile, BK=64, m201-style 2-phase-per-tile GEMM ====================
// (verified R3 kernel — unchanged)
#define G2_STAGE_A(sel) do{ \
    ushort_t* _d = &lA3[(sel)*(256*64) + (w*8)*64]; \
    CP16(gA0, _d); \
    CP16(gA1, _d + 64*64); \
    CP16(gA2, _d + 128*64); \
    CP16(gA3, _d + 192*64); }while(0)
#define G2_STAGE_B(sel) do{ \
    ushort_t* _d = &lB3[(sel)*(128*64) + (w*8)*64]; \
    CP16(gB0, _d); \
    CP16(gB1, _d + 64*64); }while(0)
#define G2_ADV() do{ gA0+=64; gA1+=64; gA2+=64; gA3+=64; gB0+=64; gB1+=64; }while(0)
#define BAR()    asm volatile("s_barrier" ::: "memory")
#define LGKM0()  do{ asm volatile("s_waitcnt lgkmcnt(0)" ::: "memory"); \
                     __builtin_amdgcn_sched_barrier(0); }while(0)

__global__ __launch_bounds__(512, 2) void gemm256_kernel(
    const ushort_t* __restrict__ A, const ushort_t* __restrict__ Bm,
    ushort_t* __restrict__ C,
    int M, int N, int K, int lda, int ldb,
    long long sA, long long sB, long long sC, int gx, int gxy)
{
  __shared__ ushort_t lA3[3 * 256 * 64];   // 96 KB
  __shared__ ushort_t lB3[3 * 128 * 64];   // 48 KB
  (void)M;

  const int bpx = gridDim.x >> 3;
  const int lin = blockIdx.x;
  const int glob = (lin & 7) * bpx + (lin >> 3);   // XCD-chunked (grid % 8 == 0)
  const int bz = glob / gxy;
  const int rem = glob - bz * gxy;
  const int by = rem / gx;
  const int bx = rem - by * gx;

  A  += (size_t)bz * sA;
  Bm += (size_t)bz * sB;

  const int tid = threadIdx.x;
  const int w = tid >> 6, l = tid & 63;
  const int lm = l & 15, qd = l >> 4;
  const int wm = w >> 2, wn = w & 3;

  const int srow = l >> 3;
  const int sch  = (l & 7) ^ srow;

  const ushort_t* gA0 = A + (size_t)(by*256 +       w*8 + srow) * lda + sch*8;
  const ushort_t* gA1 = gA0 + (size_t)64  * lda;
  const ushort_t* gA2 = gA0 + (size_t)128 * lda;
  const ushort_t* gA3 = gA0 + (size_t)192 * lda;
  const ushort_t* gB0 = Bm + (size_t)(bx*128 +      w*8 + srow) * ldb + sch*8;
  const ushort_t* gB1 = gB0 + (size_t)64  * ldb;

  f32x4 acc[8][2];
  #pragma unroll
  for (int i = 0; i < 8; i++){ acc[i][0] = (f32x4){0.f,0.f,0.f,0.f}; acc[i][1] = (f32x4){0.f,0.f,0.f,0.f}; }

  // prologue: stage tiles 0 and 1 (A0[4],B0[2],A1[4],B1[2] = 12 loads)
  G2_STAGE_A(0); G2_STAGE_B(0); G2_ADV();
  G2_STAGE_A(1); G2_STAGE_B(1); G2_ADV();
  asm volatile("s_waitcnt vmcnt(6)" ::: "memory");   // tile 0 landed; tile 1 in flight
  BAR();

  const int NT = K >> 6;
  int rd = 0, st = 2;
  #pragma unroll 1
  for (int t = 0; t < NT; ++t){
    const ushort_t* sa = &lA3[rd*(256*64) + (wm*128)*64];
    const ushort_t* sb = &lB3[rd*(128*64) + (wn*32)*64];
    const bool pre = (t + 2 < NT);

    // ---------------- phase 0 : k-slot 0 ----------------
    {
      const int ch = qd ^ (lm & 7);
      bf16x8 af[8], bfr[2];
      #pragma unroll
      for (int i = 0; i < 8; i++) af[i]  = *(const bf16x8*)&sa[(i*16 + lm)*64 + ch*8];
      #pragma unroll
      for (int j = 0; j < 2; j++) bfr[j] = *(const bf16x8*)&sb[(j*16 + lm)*64 + ch*8];
      if (pre) G2_STAGE_A(st);
      BAR();
      LGKM0();
      __builtin_amdgcn_s_setprio(1);
      #pragma unroll
      for (int i = 0; i < 8; i++)
        #pragma unroll
        for (int j = 0; j < 2; j++)
          acc[i][j] = __builtin_amdgcn_mfma_f32_16x16x32_bf16(af[i], bfr[j], acc[i][j], 0, 0, 0);
      __builtin_amdgcn_s_setprio(0);
      BAR();
    }
    // ---------------- phase 1 : k-slot 1 ----------------
    {
      const int ch = (4 | qd) ^ (lm & 7);
      bf16x8 af[8], bfr[2];
      #pragma unroll
      for (int i = 0; i < 8; i++) af[i]  = *(const bf16x8*)&sa[(i*16 + lm)*64 + ch*8];
      #pragma unroll
      for (int j = 0; j < 2; j++) bfr[j] = *(const bf16x8*)&sb[(j*16 + lm)*64 + ch*8];
      if (pre) G2_STAGE_B(st);
      BAR();
      LGKM0();
      __builtin_amdgcn_s_setprio(1);
      #pragma unroll
      for (int i = 0; i < 8; i++)
        #pragma unroll
        for (int j = 0; j < 2; j++)
          acc[i][j] = __builtin_amdgcn_mfma_f32_16x16x32_bf16(af[i], bfr[j], acc[i][j], 0, 0, 0);
      __builtin_amdgcn_s_setprio(0);
    }
    if (pre) G2_ADV();
    if (t < NT - 1){
      if (pre) asm volatile("s_waitcnt vmcnt(6)" ::: "memory");
      else     asm volatile("s_waitcnt vmcnt(0)" ::: "memory");
      BAR();
    }
    rd = (rd == 2) ? 0 : rd + 1;
    st = (st == 2) ? 0 : st + 1;
  }

  // C/D layout: col = lane&15, row = (lane>>4)*4 + reg   [verified m89/m91]
  const int row0 = by*256 + wm*128 + qd*4;
  const int col0 = bx*128 + wn*32 + lm;
  ushort_t* Cp = C + (size_t)bz * sC;
  #pragma unroll
  for (int j = 0; j < 2; j++)
    #pragma unroll
    for (int i = 0; i < 8; i++)
      #pragma unroll
      for (int r = 0; r < 4; r++)
        Cp[(size_t)(row0 + i*16 + r) * N + col0 + j*16] = f2b(acc[i][j][r]);
}

// ----- banded l_att stencil on km: qm2[t] = sum_s w[t,s]*km[b,s]; gates from kw -----
__global__ __launch_bounds__(256) void band_kernel(
    const ushort_t* __restrict__ kmb, const float* __restrict__ mask_src,
    const float* __restrict__ steps, const float* __restrict__ kw,
    const float* __restrict__ bg, ushort_t* __restrict__ qm2b,
    float* __restrict__ gates)
{
  __shared__ float shw[8][17];
  __shared__ int shslo[8];
  int bx0 = blockIdx.x;
  int bx = (bx0 & 7) * 128 + (bx0 >> 3);   // bijective: b = bx0&7 stays on its XCD
  int b = bx >> 7, t0 = (bx & 127) * 8;
  int tid = threadIdx.x;

  if (tid < 8){
    int t = t0 + tid;
    float c = steps[b] * (float)t;
    int slo = (int)ceilf(c - 8.0f);
    float w[17], m = -3e38f;
    #pragma unroll
    for (int i = 0; i < 17; i++){
      int s = slo + i;
      float l = -3e38f;
      if (s >= 0 && s < SS){
        float dd = (float)s - c;
        l = -dd*dd*(1.0f/0.3f) - INF_*(1.0f - mask_src[b*SS + s]);
      }
      w[i] = l; m = fmaxf(m, l);
    }
    float norm = 0.f, ga = 0.f;
    #pragma unroll
    for (int i = 0; i < 17; i++){
      float e = __expf(w[i] - m);
      int s = slo + i;
      if (s >= 0 && s < SS) ga += e * kw[b*SS + s]; else e = 0.f;
      w[i] = e; norm += e;
    }
    float inv = 1.0f / norm;
    #pragma unroll
    for (int i = 0; i < 17; i++) shw[tid][i] = w[i] * inv;
    shslo[tid] = slo;
    gates[b*TT + t] = 1.0f / (1.0f + __expf(-(ga*inv + bg[0])));
  }
  __syncthreads();

  int smin = shslo[0], smax = shslo[7] + 16;
  if (smin < 0) smin = 0;
  if (smax > SS-1) smax = SS-1;
  int d0 = tid * 4;
  float acc[8][4];
  #pragma unroll
  for (int t = 0; t < 8; t++){ acc[t][0]=0.f; acc[t][1]=0.f; acc[t][2]=0.f; acc[t][3]=0.f; }

  const ushort_t* kbase = kmb + ((size_t)b*SS)*DD + d0;
  for (int s = smin; s <= smax; s++){
    ushort4 kv = *(const ushort4*)(kbase + (size_t)s*DD);
    float k0 = b2f(kv.x), k1 = b2f(kv.y), k2 = b2f(kv.z), k3 = b2f(kv.w);
    #pragma unroll
    for (int t = 0; t < 8; t++){
      unsigned u = (unsigned)(s - shslo[t]);
      if (u < 17u){
        float wgt = shw[t][u];
        acc[t][0] += wgt*k0; acc[t][1] += wgt*k1; acc[t][2] += wgt*k2; acc[t][3] += wgt*k3;
      }
    }
  }
  #pragma unroll
  for (int t = 0; t < 8; t++){
    ushort4 o; o.x=f2b(acc[t][0]); o.y=f2b(acc[t][1]); o.z=f2b(acc[t][2]); o.w=f2b(acc[t][3]);
    *(ushort4*)(qm2b + ((size_t)(b*TT + t0 + t))*DD + d0) = o;
  }
}

// ------- fused softmax((dots_bf16+cv)/scale) + exact l_att + gated mix -> fp32 out -------
__device__ __forceinline__ void blkmax2(float& v1, float& v2, float* sh8){
  #pragma unroll
  for (int o = 32; o; o >>= 1){
    v1 = fmaxf(v1, __shfl_xor(v1, o));
    v2 = fmaxf(v2, __shfl_xor(v2, o));
  }
  int wv = threadIdx.x >> 6;
  if ((threadIdx.x & 63) == 0){ sh8[wv] = v1; sh8[4+wv] = v2; }
  __syncthreads();
  v1 = fmaxf(fmaxf(sh8[0], sh8[1]), fmaxf(sh8[2], sh8[3]));
  v2 = fmaxf(fmaxf(sh8[4], sh8[5]), fmaxf(sh8[6], sh8[7]));
}
__device__ __forceinline__ void blksum2(float& v1, float& v2, float* sh8){
  #pragma unroll
  for (int o = 32; o; o >>= 1){
    v1 += __shfl_xor(v1, o);
    v2 += __shfl_xor(v2, o);
  }
  int wv = threadIdx.x >> 6;
  if ((threadIdx.x & 63) == 0){ sh8[wv] = v1; sh8[4+wv] = v2; }
  __syncthreads();
  v1 = sh8[0]+sh8[1]+sh8[2]+sh8[3];
  v2 = sh8[4]+sh8[5]+sh8[6]+sh8[7];
}

__global__ __launch_bounds__(256) void softmax_mix_kernel(
    const ushort_t* __restrict__ dotsb, float* __restrict__ out,
    const float* __restrict__ mask_src, const float* __restrict__ steps,
    const float* __restrict__ gates, const float* __restrict__ cv)
{
  __shared__ float shA[8];
  __shared__ float shB[8];
  int blk0 = blockIdx.x;
  int blk = (blk0 & 7) * 1024 + (blk0 >> 3);   // bijective: b = blk0&7 stays on its XCD
  int b = blk >> 10, t = blk & 1023;
  int tid = threadIdx.x;
  int s0 = tid * 4;
  float c = steps[b] * (float)t;

  ushort4 dv = *(const ushort4*)(dotsb + (size_t)blk*SS + s0);
  float4 mv = *(const float4*)(mask_src + (size_t)b*SS + s0);
  float4 cva = *(const float4*)(cv + (size_t)b*SS + s0);
  float dvf[4] = {b2f(dv.x) + cva.x, b2f(dv.y) + cva.y, b2f(dv.z) + cva.z, b2f(dv.w) + cva.w};
  float msk[4] = {mv.x, mv.y, mv.z, mv.w};
  float dl[4], ll[4];
  float dmax = -3e38f, lmax = -3e38f;
  #pragma unroll
  for (int r = 0; r < 4; r++){
    float im = INF_ * (1.0f - msk[r]);
    dl[r] = (dvf[r] - im) * (1.0f/32.0f);          // scale = sqrt(1024) = 32
    float dd = (float)(s0 + r) - c;
    ll[r] = -dd*dd*(1.0f/0.3f) - im;
    dmax = fmaxf(dmax, dl[r]);
    lmax = fmaxf(lmax, ll[r]);
  }
  blkmax2(dmax, lmax, shA);
  float ps[4], lp[4];
  float psum = 0.f, lsum = 0.f;
  #pragma unroll
  for (int r = 0; r < 4; r++){
    ps[r] = __expf(dl[r] - dmax); psum += ps[r];
    lp[r] = __expf(ll[r] - lmax); lsum += lp[r];
  }
  blksum2(psum, lsum, shB);

  float g = gates[blk];
  float ip = (1.0f - g) / psum, il = g / lsum;
  float4 ov;
  ov.x = ps[0]*ip + lp[0]*il;
  ov.y = ps[1]*ip + lp[1]*il;
  ov.z = ps[2]*ip + lp[2]*il;
  ov.w = ps[3]*ip + lp[3]*il;
  *(float4*)(out + (size_t)blk*SS + s0) = ov;
}

extern "C" void kernel_launch(void* const* d_in, const int* in_sizes, int n_in,
                              void* d_out, int out_size, void* d_ws, size_t ws_size,
                              hipStream_t stream)
{
  const float* key      = (const float*)d_in[0];
  const float* mask_src = (const float*)d_in[1];
  const float* mask_trg = (const float*)d_in[2];
  const float* Wq       = (const float*)d_in[3];
  const float* bq       = (const float*)d_in[4];
  const float* Wk       = (const float*)d_in[5];
  const float* bk       = (const float*)d_in[6];
  const float* wg       = (const float*)d_in[7];
  const float* bg       = (const float*)d_in[8];
  float* out = (float*)d_out;   // fp32 [B,T,S] = 32 MB, written ONLY by softmax
  (void)bk;  // bk contributes only a row-constant softmax shift -> cancels

  // ws layout (~54.3 MB):
  char* ws = (char*)d_ws;
  float* steps     = (float*)ws;                         // 32 B
  float* gates     = (float*)(ws + 4096);                // 32 KB
  float* cv        = (float*)(ws + 4096 + 32768);        // 32 KB
  float* kw        = (float*)(ws + 4096 + 65536);        // 32 KB
  float* v2        = (float*)(ws + 4096 + 98304);        // 4 KB
  ushort_t* WqTb   = (ushort_t*)(ws + 131072);           // 2 MB
  ushort_t* WkTb   = WqTb + (size_t)DD*DD;               // 2 MB
  ushort_t* WmTb   = WkTb + (size_t)DD*DD;               // 2 MB
  ushort_t* keyb   = WmTb + (size_t)DD*DD;               // 16 MB
  ushort_t* kmb    = keyb + (size_t)BB*SS*DD;            // 16 MB (km; DEAD after band -> reused as dotsb)
  char* shared16   = (char*)(kmb + (size_t)BB*SS*DD);    // 16 MB: WmT partials, later qm2b
  float* wmPart    = (float*)shared16;                   // 4 x 1M fp32
  ushort_t* qm2b   = (ushort_t*)shared16;                // 16 MB (after the fused reduce)
  ushort_t* dotsb  = kmb;                                // bf16 dots in km's dead slot

  // === MEASUREMENT ROUND #2: pre, gemm_bt, key_convert, band, softmax each launched
  // TWICE (all pure functions of their inputs -> outputs bit-identical).
  // dur_us delta vs R4 (211.96) = t_pre + t_wmt + t_keyconv + t_band + t_softmax.
  // gemm256 pair stays single (measured in R5: t_km + t_dots = 45.8 us).

  // 1) transposes + steps + v2 (atomic-free)
  pre_kernel<<<2064, 256, 0, stream>>>(Wq, Wk, WqTb, WkTb, mask_src, mask_trg, steps, v2, bq);
  pre_kernel<<<2064, 256, 0, stream>>>(Wq, Wk, WqTb, WkTb, mask_src, mask_trg, steps, v2, bq);
  // 2) WmT[f,e] = sum_d Wk[d,f] Wq[d,e] = WkT @ WqT^T, split-K=4 over d -> fp32 partials
  gemm_bt_kernel<<<256, 256, 0, stream>>>(
      WkTb, WqTb, nullptr, (void*)wmPart, DD, DD, DD/4, DD, DD,
      DD/4, DD/4, (long long)DD*DD, 0, 0, 8, 64);
  gemm_bt_kernel<<<256, 256, 0, stream>>>(
      WkTb, WqTb, nullptr, (void*)wmPart, DD, DD, DD/4, DD, DD,
      DD/4, DD/4, (long long)DD*DD, 0, 0, 8, 64);
  // 3) key convert + kw/cv, fused with the WmT partial reduce (blocks >= BB*SS)
  key_convert_kernel<<<BB*SS + 1024, 256, 0, stream>>>(
      key, wg, v2, keyb, kw, cv, wmPart, WmTb);
  key_convert_kernel<<<BB*SS + 1024, 256, 0, stream>>>(
      key, wg, v2, keyb, kw, cv, wmPart, WmTb);
  // 4) km = keyb @ Wm   [8192 x 1024 x 1024] -> bf16
  gemm256_kernel<<<256, 512, 0, stream>>>(
      keyb, WmTb, kmb, BB*SS, DD, DD, DD, DD, 0, 0, 0, 8, 256);
  // 5) qm2 = l_att · km (banded) + gates  (XCD-affine)
  band_kernel<<<BB*TT/8, 256, 0, stream>>>(kmb, mask_src, steps, kw, bg, qm2b, gates);
  band_kernel<<<BB*TT/8, 256, 0, stream>>>(kmb, mask_src, steps, kw, bg, qm2b, gates);
  // 6) dots[b] = qm2[b] @ keyb[b]^T -> dotsb (one batch per XCD)
  gemm256_kernel<<<256, 512, 0, stream>>>(
      qm2b, keyb, dotsb, TT, SS, DD, DD, DD,
      (long long)TT*DD, (long long)SS*DD, (long long)TT*SS, 8, 32);
  // 7) softmax + exact l_att + gated mix (XCD-affine)
  softmax_mix_kernel<<<BB*TT, 256, 0, stream>>>(dotsb, out, mask_src, steps, gates, cv);
  softmax_mix_kernel<<<BB*TT, 256, 0, stream>>>(dotsb, out, mask_src, steps, gates, cv);
}

// Round 7
// 198.593 us; speedup vs baseline: 1.4152x; 1.4152x over previous
//
#include <hip/hip_runtime.h>
#include <hip/hip_bf16.h>
#include <stdint.h>

typedef unsigned short ushort_t;

#define BB 8
#define SS 1024
#define TT 1024
#define DD 1024
#define INF_ 1e10f

__device__ __forceinline__ float b2f(ushort_t u){
  union { unsigned u32; float f; } x; x.u32 = ((unsigned)u) << 16; return x.f;
}
__device__ __forceinline__ ushort_t f2b(float f){
  union { float f; unsigned u; } x; x.f = f;
  unsigned r = x.u + 0x7FFFu + ((x.u >> 16) & 1u);
  return (ushort_t)(r >> 16);
}

// ---- preamble: blocks 0..2047 transpose Wq/Wk -> bf16; 2048..2055 steps;
//      blocks 2056..2119 v2[f] = sum_d Wk[d,f]*bq[d] (64 blocks, atomic-free) ----
__global__ __launch_bounds__(256) void pre_kernel(
    const float* __restrict__ Wq, const float* __restrict__ Wk,
    ushort_t* __restrict__ WqT, ushort_t* __restrict__ WkT,
    const float* __restrict__ msrc, const float* __restrict__ mtrg,
    float* __restrict__ steps, float* __restrict__ v2,
    const float* __restrict__ bq)
{
  __shared__ float tile[32][33];
  __shared__ float sh[8];
  __shared__ float shv[256];
  int blk = blockIdx.x, tid = threadIdx.x;
  if (blk < 2048){
    const float* src = (blk >= 1024) ? Wk : Wq;
    ushort_t* dst = (blk >= 1024) ? WkT : WqT;
    int q = blk & 1023;
    int tx = q & 31, ty = q >> 5;
    int c = tid & 31, r0 = tid >> 5;
    #pragma unroll
    for (int k = 0; k < 4; k++){
      int r = r0 + k*8;
      tile[r][c] = src[(size_t)(ty*32 + r)*DD + tx*32 + c];
    }
    __syncthreads();
    #pragma unroll
    for (int k = 0; k < 4; k++){
      int r = r0 + k*8;
      dst[(size_t)(tx*32 + r)*DD + ty*32 + c] = f2b(tile[c][r]);
    }
  } else if (blk < 2056){
    int b = blk - 2048;
    float a = 0.f, c = 0.f;
    for (int i = tid; i < SS; i += 256) a += msrc[b*SS + i];
    for (int i = tid; i < TT; i += 256) c += mtrg[b*TT + i];
    #pragma unroll
    for (int o = 32; o; o >>= 1){ a += __shfl_xor(a, o); c += __shfl_xor(c, o); }
    int wv = tid >> 6, ln = tid & 63;
    if (!ln){ sh[wv] = a; sh[4+wv] = c; }
    __syncthreads();
    if (!tid){
      float sa = sh[0]+sh[1]+sh[2]+sh[3];
      float sc = sh[4]+sh[5]+sh[6]+sh[7];
      steps[b] = sa / sc;
    }
  } else {
    // v2: 64 blocks x 16 cols; 16 d-groups of 64 per col, LDS reduce (R6 post-mortem:
    // the 8-block version serialized pre's tail ~5-8 us on 8 CUs).
    int b2 = blk - 2056;                 // 0..63
    int col = b2*16 + (tid & 15);
    int grp = tid >> 4;                  // 0..15
    float a = 0.f;
    const float* Wp = Wk + (size_t)(grp*64)*DD + col;
    for (int d = 0; d < 64; ++d) a += Wp[(size_t)d*DD] * bq[grp*64 + d];
    shv[grp*16 + (tid & 15)] = a;
    __syncthreads();
    if (grp == 0){
      float s = 0.f;
      #pragma unroll
      for (int g = 0; g < 16; g++) s += shv[g*16 + tid];
      v2[col] = s;
    }
  }
}

// ------- key rows fp32->bf16 + kw = key·wg, cv = key·v2; blocks >= BB*SS do the
//         WmT split-K reduce (4 fp32 partials -> bf16), fused to save a dispatch -------
__global__ __launch_bounds__(256) void key_convert_kernel(
    const float* __restrict__ key, const float* __restrict__ wg,
    const float* __restrict__ v2f, ushort_t* __restrict__ keyb,
    float* __restrict__ kw, float* __restrict__ cv,
    const float* __restrict__ part, ushort_t* __restrict__ wmt)
{
  __shared__ float sh[8];
  int blk = blockIdx.x;
  if (blk >= BB*SS){
    int i4 = (blk - BB*SS) * 256 + threadIdx.x;   // float4 idx, n = 1024*1024/4
    const float4* p = (const float4*)part;
    float4 a = p[i4];
    float4 b = p[i4 + 262144];
    float4 c = p[i4 + 524288];
    float4 d = p[i4 + 786432];
    ushort4 o;
    o.x = f2b(a.x + b.x + c.x + d.x);
    o.y = f2b(a.y + b.y + c.y + d.y);
    o.z = f2b(a.z + b.z + c.z + d.z);
    o.w = f2b(a.w + b.w + c.w + d.w);
    ((ushort4*)wmt)[i4] = o;
    return;
  }
  int row = blk;              // b*SS + s
  int tid = threadIdx.x, d0 = tid*4;
  float4 v = *(const float4*)(key + (size_t)row*DD + d0);
  ushort4 o; o.x=f2b(v.x); o.y=f2b(v.y); o.z=f2b(v.z); o.w=f2b(v.w);
  *(ushort4*)(keyb + (size_t)row*DD + d0) = o;
  float4 w4 = *(const float4*)(wg + d0);
  float4 u4 = *(const float4*)(v2f + d0);
  float pk = v.x*w4.x + v.y*w4.y + v.z*w4.z + v.w*w4.w;
  float pc = v.x*u4.x + v.y*u4.y + v.z*u4.z + v.w*u4.w;
  #pragma unroll
  for (int off = 32; off; off >>= 1){ pk += __shfl_xor(pk, off); pc += __shfl_xor(pc, off); }
  int wvv = tid >> 6;
  if ((tid & 63) == 0){ sh[wvv] = pk; sh[4+wvv] = pc; }
  __syncthreads();
  if (!tid){
    kw[row] = sh[0]+sh[1]+sh[2]+sh[3];
    cv[row] = sh[4]+sh[5]+sh[6]+sh[7];
  }
}

// ---- m97-style bf16 GEMM (kept for the small WmT = WkT@WqT^T split-K GEMM) ----
typedef __bf16 bf16x8 __attribute__((ext_vector_type(8)));
typedef float f32x4 __attribute__((ext_vector_type(4)));

#define CP16(g, l) __builtin_amdgcn_global_load_lds( \
    (const __attribute__((address_space(1))) void*)(g), \
    (__attribute__((address_space(3))) void*)(l), 16, 0, 0)

__global__ __launch_bounds__(256, 2) void gemm_bt_kernel(
    const ushort_t* __restrict__ A, const ushort_t* __restrict__ Bm,
    const float* __restrict__ bias, void* __restrict__ Cv,
    int M, int N, int K, int lda, int ldb,
    long long sA, long long sB, long long sC, int hasBias, int outBF16,
    int gx, int gxy)
{
  __shared__ ushort_t lA[128*32];
  __shared__ ushort_t lB[128*32];

  const int bpx = gridDim.x >> 3;
  const int lin = blockIdx.x;
  const int glob = (lin & 7) * bpx + (lin >> 3);
  const int bz = glob / gxy;
  const int rem = glob - bz * gxy;
  const int by = rem / gx;
  const int bx = rem - by * gx;

  A  += (size_t)bz * sA;
  Bm += (size_t)bz * sB;

  const int tid = threadIdx.x;
  const int wv = tid >> 6, ln = tid & 63;
  const int r4 = ln >> 2, c8 = (ln & 3) * 8;

  const ushort_t* gA0 = A  + (size_t)(by*128 + wv*32 + r4) * lda + c8;
  const ushort_t* gA1 = gA0 + (size_t)16 * lda;
  const ushort_t* gB0 = Bm + (size_t)(bx*128 + wv*32 + r4) * ldb + c8;
  const ushort_t* gB1 = gB0 + (size_t)16 * ldb;
  ushort_t* lA0 = &lA[(wv*32     ) * 32];
  ushort_t* lA1 = &lA[(wv*32 + 16) * 32];
  ushort_t* lB0 = &lB[(wv*32     ) * 32];
  ushort_t* lB1 = &lB[(wv*32 + 16) * 32];

  const int lm = ln & 15, qd = ln >> 4;
  const int wm = (wv >> 1) * 64, wn = (wv & 1) * 64;

  f32x4 acc[4][4];
  #pragma unroll
  for (int i = 0; i < 4; i++)
    #pragma unroll
    for (int j = 0; j < 4; j++) acc[i][j] = (f32x4){0.f, 0.f, 0.f, 0.f};

  for (int k0 = 0; k0 < K; k0 += 32){
    CP16(gA0, lA0); CP16(gA1, lA1); CP16(gB0, lB0); CP16(gB1, lB1);
    gA0 += 32; gA1 += 32; gB0 += 32; gB1 += 32;
    __syncthreads();
    bf16x8 af[4], bf[4];
    #pragma unroll
    for (int i = 0; i < 4; i++) af[i] = *(const bf16x8*)&lA[(wm + i*16 + lm)*32 + qd*8];
    #pragma unroll
    for (int j = 0; j < 4; j++) bf[j] = *(const bf16x8*)&lB[(wn + j*16 + lm)*32 + qd*8];
    #pragma unroll
    for (int i = 0; i < 4; i++)
      #pragma unroll
      for (int j = 0; j < 4; j++)
        acc[i][j] = __builtin_amdgcn_mfma_f32_16x16x32_bf16(af[i], bf[j], acc[i][j], 0, 0, 0);
    __syncthreads();
  }

  // C/D layout: col = lane&15, row = (lane>>4)*4 + reg   [verified m89/m91]
  const int row0 = by*128 + wm + qd*4;
  const int col0 = bx*128 + wn + lm;
  ushort_t* Cb = (ushort_t*)Cv + (size_t)bz * sC;
  float*    Cf = (float*)Cv    + (size_t)bz * sC;
  #pragma unroll
  for (int j = 0; j < 4; j++){
    int col = col0 + j*16;
    float bv = hasBias ? bias[col] : 0.f;
    #pragma unroll
    for (int i = 0; i < 4; i++)
      #pragma unroll
      for (int r = 0; r < 4; r++){
        size_t idx = (size_t)(row0 + i*16 + r) * N + col;
        float v = acc[i][j][r] + bv;
        if (outBF16) Cb[idx] = f2b(v); else Cf[idx] = v;
      }
  }
}

// ==================== 256x128-tile, BK=64, 2-phase-per-tile GEMM ====================
// R7 change: wave layout 2Mx4N -> 4Mx2N (per-wave 64x64 output). LDS-read traffic per
// K-tile: 4xA+2xB = 160KB -> 2xA+4xB = 128KB (A re-read by 2 col-waves instead of 4),
// and 8 instead of 10 ds_read_b128 per phase. Theory: kernel is LDS-read bound
// (~12.5us model vs 6.9us MFMA floor). Staging/barriers/vmcnt identical to R3's
// verified schedule.
#define G2_STAGE_A(sel) do{ \
    ushort_t* _d = &lA3[(sel)*(256*64) + (w*8)*64]; \
    CP16(gA0, _d); \
    CP16(gA1, _d + 64*64); \
    CP16(gA2, _d + 128*64); \
    CP16(gA3, _d + 192*64); }while(0)
#define G2_STAGE_B(sel) do{ \
    ushort_t* _d = &lB3[(sel)*(128*64) + (w*8)*64]; \
    CP16(gB0, _d); \
    CP16(gB1, _d + 64*64); }while(0)
#define G2_ADV() do{ gA0+=64; gA1+=64; gA2+=64; gA3+=64; gB0+=64; gB1+=64; }while(0)
#define BAR()    asm volatile("s_barrier" ::: "memory")
#define LGKM0()  do{ asm volatile("s_waitcnt lgkmcnt(0)" ::: "memory"); \
                     __builtin_amdgcn_sched_barrier(0); }while(0)

__global__ __launch_bounds__(512, 2) void gemm256_kernel(
    const ushort_t* __restrict__ A, const ushort_t* __restrict__ Bm,
    ushort_t* __restrict__ C,
    int M, int N, int K, int lda, int ldb,
    long long sA, long long sB, long long sC, int gx, int gxy)
{
  __shared__ ushort_t lA3[3 * 256 * 64];   // 96 KB
  __shared__ ushort_t lB3[3 * 128 * 64];   // 48 KB
  (void)M;

  const int bpx = gridDim.x >> 3;
  const int lin = blockIdx.x;
  const int glob = (lin & 7) * bpx + (lin >> 3);   // XCD-chunked (grid % 8 == 0)
  const int bz = glob / gxy;
  const int rem = glob - bz * gxy;
  const int by = rem / gx;
  const int bx = rem - by * gx;

  A  += (size_t)bz * sA;
  Bm += (size_t)bz * sB;

  const int tid = threadIdx.x;
  const int w = tid >> 6, l = tid & 63;
  const int lm = l & 15, qd = l >> 4;
  const int wm = w & 3, wn = w >> 2;     // 4M x 2N wave grid

  const int srow = l >> 3;
  const int sch  = (l & 7) ^ srow;

  const ushort_t* gA0 = A + (size_t)(by*256 +       w*8 + srow) * lda + sch*8;
  const ushort_t* gA1 = gA0 + (size_t)64  * lda;
  const ushort_t* gA2 = gA0 + (size_t)128 * lda;
  const ushort_t* gA3 = gA0 + (size_t)192 * lda;
  const ushort_t* gB0 = Bm + (size_t)(bx*128 +      w*8 + srow) * ldb + sch*8;
  const ushort_t* gB1 = gB0 + (size_t)64  * ldb;

  f32x4 acc[4][4];
  #pragma unroll
  for (int i = 0; i < 4; i++)
    #pragma unroll
    for (int j = 0; j < 4; j++) acc[i][j] = (f32x4){0.f,0.f,0.f,0.f};

  // prologue: stage tiles 0 and 1 (A0[4],B0[2],A1[4],B1[2] = 12 loads)
  G2_STAGE_A(0); G2_STAGE_B(0); G2_ADV();
  G2_STAGE_A(1); G2_STAGE_B(1); G2_ADV();
  asm volatile("s_waitcnt vmcnt(6)" ::: "memory");   // tile 0 landed; tile 1 in flight
  BAR();

  const int NT = K >> 6;
  int rd = 0, st = 2;
  #pragma unroll 1
  for (int t = 0; t < NT; ++t){
    const ushort_t* sa = &lA3[rd*(256*64) + (wm*64)*64];
    const ushort_t* sb = &lB3[rd*(128*64) + (wn*64)*64];
    const bool pre = (t + 2 < NT);

    // ---------------- phase 0 : k-slot 0 ----------------
    {
      const int ch = qd ^ (lm & 7);
      bf16x8 af[4], bfr[4];
      #pragma unroll
      for (int i = 0; i < 4; i++) af[i]  = *(const bf16x8*)&sa[(i*16 + lm)*64 + ch*8];
      #pragma unroll
      for (int j = 0; j < 4; j++) bfr[j] = *(const bf16x8*)&sb[(j*16 + lm)*64 + ch*8];
      if (pre) G2_STAGE_A(st);
      BAR();
      LGKM0();
      __builtin_amdgcn_s_setprio(1);
      #pragma unroll
      for (int i = 0; i < 4; i++)
        #pragma unroll
        for (int j = 0; j < 4; j++)
          acc[i][j] = __builtin_amdgcn_mfma_f32_16x16x32_bf16(af[i], bfr[j], acc[i][j], 0, 0, 0);
      __builtin_amdgcn_s_setprio(0);
      BAR();
    }
    // ---------------- phase 1 : k-slot 1 ----------------
    {
      const int ch = (4 | qd) ^ (lm & 7);
      bf16x8 af[4], bfr[4];
      #pragma unroll
      for (int i = 0; i < 4; i++) af[i]  = *(const bf16x8*)&sa[(i*16 + lm)*64 + ch*8];
      #pragma unroll
      for (int j = 0; j < 4; j++) bfr[j] = *(const bf16x8*)&sb[(j*16 + lm)*64 + ch*8];
      if (pre) G2_STAGE_B(st);
      BAR();
      LGKM0();
      __builtin_amdgcn_s_setprio(1);
      #pragma unroll
      for (int i = 0; i < 4; i++)
        #pragma unroll
        for (int j = 0; j < 4; j++)
          acc[i][j] = __builtin_amdgcn_mfma_f32_16x16x32_bf16(af[i], bfr[j], acc[i][j], 0, 0, 0);
      __builtin_amdgcn_s_setprio(0);
    }
    if (pre) G2_ADV();
    if (t < NT - 1){
      if (pre) asm volatile("s_waitcnt vmcnt(6)" ::: "memory");
      else     asm volatile("s_waitcnt vmcnt(0)" ::: "memory");
      BAR();
    }
    rd = (rd == 2) ? 0 : rd + 1;
    st = (st == 2) ? 0 : st + 1;
  }

  // C/D layout: col = lane&15, row = (lane>>4)*4 + reg   [verified m89/m91]
  const int row0 = by*256 + wm*64 + qd*4;
  const int col0 = bx*128 + wn*64 + lm;
  ushort_t* Cp = C + (size_t)bz * sC;
  #pragma unroll
  for (int j = 0; j < 4; j++)
    #pragma unroll
    for (int i = 0; i < 4; i++)
      #pragma unroll
      for (int r = 0; r < 4; r++)
        Cp[(size_t)(row0 + i*16 + r) * N + col0 + j*16] = f2b(acc[i][j][r]);
}

// ----- banded l_att stencil on km: qm2[t] = sum_s w[t,s]*km[b,s]; gates from kw -----
__global__ __launch_bounds__(256) void band_kernel(
    const ushort_t* __restrict__ kmb, const float* __restrict__ mask_src,
    const float* __restrict__ steps, const float* __restrict__ kw,
    const float* __restrict__ bg, ushort_t* __restrict__ qm2b,
    float* __restrict__ gates)
{
  __shared__ float shw[8][17];
  __shared__ int shslo[8];
  int bx0 = blockIdx.x;
  int bx = (bx0 & 7) * 128 + (bx0 >> 3);   // bijective: b = bx0&7 stays on its XCD
  int b = bx >> 7, t0 = (bx & 127) * 8;
  int tid = threadIdx.x;

  if (tid < 8){
    int t = t0 + tid;
    float c = steps[b] * (float)t;
    int slo = (int)ceilf(c - 8.0f);
    float w[17], m = -3e38f;
    #pragma unroll
    for (int i = 0; i < 17; i++){
      int s = slo + i;
      float l = -3e38f;
      if (s >= 0 && s < SS){
        float dd = (float)s - c;
        l = -dd*dd*(1.0f/0.3f) - INF_*(1.0f - mask_src[b*SS + s]);
      }
      w[i] = l; m = fmaxf(m, l);
    }
    float norm = 0.f, ga = 0.f;
    #pragma unroll
    for (int i = 0; i < 17; i++){
      float e = __expf(w[i] - m);
      int s = slo + i;
      if (s >= 0 && s < SS) ga += e * kw[b*SS + s]; else e = 0.f;
      w[i] = e; norm += e;
    }
    float inv = 1.0f / norm;
    #pragma unroll
    for (int i = 0; i < 17; i++) shw[tid][i] = w[i] * inv;
    shslo[tid] = slo;
    gates[b*TT + t] = 1.0f / (1.0f + __expf(-(ga*inv + bg[0])));
  }
  __syncthreads();

  int smin = shslo[0], smax = shslo[7] + 16;
  if (smin < 0) smin = 0;
  if (smax > SS-1) smax = SS-1;
  int d0 = tid * 4;
  float acc[8][4];
  #pragma unroll
  for (int t = 0; t < 8; t++){ acc[t][0]=0.f; acc[t][1]=0.f; acc[t][2]=0.f; acc[t][3]=0.f; }

  const ushort_t* kbase = kmb + ((size_t)b*SS)*DD + d0;
  for (int s = smin; s <= smax; s++){
    ushort4 kv = *(const ushort4*)(kbase + (size_t)s*DD);
    float k0 = b2f(kv.x), k1 = b2f(kv.y), k2 = b2f(kv.z), k3 = b2f(kv.w);
    #pragma unroll
    for (int t = 0; t < 8; t++){
      unsigned u = (unsigned)(s - shslo[t]);
      if (u < 17u){
        float wgt = shw[t][u];
        acc[t][0] += wgt*k0; acc[t][1] += wgt*k1; acc[t][2] += wgt*k2; acc[t][3] += wgt*k3;
      }
    }
  }
  #pragma unroll
  for (int t = 0; t < 8; t++){
    ushort4 o; o.x=f2b(acc[t][0]); o.y=f2b(acc[t][1]); o.z=f2b(acc[t][2]); o.w=f2b(acc[t][3]);
    *(ushort4*)(qm2b + ((size_t)(b*TT + t0 + t))*DD + d0) = o;
  }
}

// ------- fused softmax((dots_bf16+cv)/scale) + exact l_att + gated mix -> fp32 out -------
__device__ __forceinline__ void blkmax2(float& v1, float& v2, float* sh8){
  #pragma unroll
  for (int o = 32; o; o >>= 1){
    v1 = fmaxf(v1, __shfl_xor(v1, o));
    v2 = fmaxf(v2, __shfl_xor(v2, o));
  }
  int wv = threadIdx.x >> 6;
  if ((threadIdx.x & 63) == 0){ sh8[wv] = v1; sh8[4+wv] = v2; }
  __syncthreads();
  v1 = fmaxf(fmaxf(sh8[0], sh8[1]), fmaxf(sh8[2], sh8[3]));
  v2 = fmaxf(fmaxf(sh8[4], sh8[5]), fmaxf(sh8[6], sh8[7]));
}
__device__ __forceinline__ void blksum2(float& v1, float& v2, float* sh8){
  #pragma unroll
  for (int o = 32; o; o >>= 1){
    v1 += __shfl_xor(v1, o);
    v2 += __shfl_xor(v2, o);
  }
  int wv = threadIdx.x >> 6;
  if ((threadIdx.x & 63) == 0){ sh8[wv] = v1; sh8[4+wv] = v2; }
  __syncthreads();
  v1 = sh8[0]+sh8[1]+sh8[2]+sh8[3];
  v2 = sh8[4]+sh8[5]+sh8[6]+sh8[7];
}

__global__ __launch_bounds__(256) void softmax_mix_kernel(
    const ushort_t* __restrict__ dotsb, float* __restrict__ out,
    const float* __restrict__ mask_src, const float* __restrict__ steps,
    const float* __restrict__ gates, const float* __restrict__ cv)
{
  __shared__ float shA[8];
  __shared__ float shB[8];
  int blk0 = blockIdx.x;
  int blk = (blk0 & 7) * 1024 + (blk0 >> 3);   // bijective: b = blk0&7 stays on its XCD
  int b = blk >> 10, t = blk & 1023;
  int tid = threadIdx.x;
  int s0 = tid * 4;
  float c = steps[b] * (float)t;

  ushort4 dv = *(const ushort4*)(dotsb + (size_t)blk*SS + s0);
  float4 mv = *(const float4*)(mask_src + (size_t)b*SS + s0);
  float4 cva = *(const float4*)(cv + (size_t)b*SS + s0);
  float dvf[4] = {b2f(dv.x) + cva.x, b2f(dv.y) + cva.y, b2f(dv.z) + cva.z, b2f(dv.w) + cva.w};
  float msk[4] = {mv.x, mv.y, mv.z, mv.w};
  float dl[4], ll[4];
  float dmax = -3e38f, lmax = -3e38f;
  #pragma unroll
  for (int r = 0; r < 4; r++){
    float im = INF_ * (1.0f - msk[r]);
    dl[r] = (dvf[r] - im) * (1.0f/32.0f);          // scale = sqrt(1024) = 32
    float dd = (float)(s0 + r) - c;
    ll[r] = -dd*dd*(1.0f/0.3f) - im;
    dmax = fmaxf(dmax, dl[r]);
    lmax = fmaxf(lmax, ll[r]);
  }
  blkmax2(dmax, lmax, shA);
  float ps[4], lp[4];
  float psum = 0.f, lsum = 0.f;
  #pragma unroll
  for (int r = 0; r < 4; r++){
    ps[r] = __expf(dl[r] - dmax); psum += ps[r];
    lp[r] = __expf(ll[r] - lmax); lsum += lp[r];
  }
  blksum2(psum, lsum, shB);

  float g = gates[blk];
  float ip = (1.0f - g) / psum, il = g / lsum;
  float4 ov;
  ov.x = ps[0]*ip + lp[0]*il;
  ov.y = ps[1]*ip + lp[1]*il;
  ov.z = ps[2]*ip + lp[2]*il;
  ov.w = ps[3]*ip + lp[3]*il;
  *(float4*)(out + (size_t)blk*SS + s0) = ov;
}

extern "C" void kernel_launch(void* const* d_in, const int* in_sizes, int n_in,
                              void* d_out, int out_size, void* d_ws, size_t ws_size,
                              hipStream_t stream)
{
  const float* key      = (const float*)d_in[0];
  const float* mask_src = (const float*)d_in[1];
  const float* mask_trg = (const float*)d_in[2];
  const float* Wq       = (const float*)d_in[3];
  const float* bq       = (const float*)d_in[4];
  const float* Wk       = (const float*)d_in[5];
  const float* bk       = (const float*)d_in[6];
  const float* wg       = (const float*)d_in[7];
  const float* bg       = (const float*)d_in[8];
  float* out = (float*)d_out;   // fp32 [B,T,S] = 32 MB, written ONLY by softmax
  (void)bk;  // bk contributes only a row-constant softmax shift -> cancels

  // ws layout (~54.3 MB):
  char* ws = (char*)d_ws;
  float* steps     = (float*)ws;                         // 32 B
  float* gates     = (float*)(ws + 4096);                // 32 KB
  float* cv        = (float*)(ws + 4096 + 32768);        // 32 KB
  float* kw        = (float*)(ws + 4096 + 65536);        // 32 KB
  float* v2        = (float*)(ws + 4096 + 98304);        // 4 KB
  ushort_t* WqTb   = (ushort_t*)(ws + 131072);           // 2 MB
  ushort_t* WkTb   = WqTb + (size_t)DD*DD;               // 2 MB
  ushort_t* WmTb   = WkTb + (size_t)DD*DD;               // 2 MB
  ushort_t* keyb   = WmTb + (size_t)DD*DD;               // 16 MB
  ushort_t* kmb    = keyb + (size_t)BB*SS*DD;            // 16 MB (km; DEAD after band -> reused as dotsb)
  char* shared16   = (char*)(kmb + (size_t)BB*SS*DD);    // 16 MB: WmT partials, later qm2b
  float* wmPart    = (float*)shared16;                   // 4 x 1M fp32
  ushort_t* qm2b   = (ushort_t*)shared16;                // 16 MB (after the fused reduce)
  ushort_t* dotsb  = kmb;                                // bf16 dots in km's dead slot

  // 1) transposes + steps + v2 (64-block, atomic-free)
  pre_kernel<<<2120, 256, 0, stream>>>(Wq, Wk, WqTb, WkTb, mask_src, mask_trg, steps, v2, bq);
  // 2) WmT[f,e] = sum_d Wk[d,f] Wq[d,e] = WkT @ WqT^T, split-K=4 over d -> fp32 partials
  gemm_bt_kernel<<<256, 256, 0, stream>>>(
      WkTb, WqTb, nullptr, (void*)wmPart, DD, DD, DD/4, DD, DD,
      DD/4, DD/4, (long long)DD*DD, 0, 0, 8, 64);
  // 3) key convert + kw/cv, fused with the WmT partial reduce (blocks >= BB*SS)
  key_convert_kernel<<<BB*SS + 1024, 256, 0, stream>>>(
      key, wg, v2, keyb, kw, cv, wmPart, WmTb);
  // 4) km = keyb @ Wm   [8192 x 1024 x 1024] -> bf16
  gemm256_kernel<<<256, 512, 0, stream>>>(
      keyb, WmTb, kmb, BB*SS, DD, DD, DD, DD, 0, 0, 0, 8, 256);
  // 5) qm2 = l_att · km (banded) + gates  (XCD-affine)
  band_kernel<<<BB*TT/8, 256, 0, stream>>>(kmb, mask_src, steps, kw, bg, qm2b, gates);
  // 6) dots[b] = qm2[b] @ keyb[b]^T -> dotsb (one batch per XCD)
  gemm256_kernel<<<256, 512, 0, stream>>>(
      qm2b, keyb, dotsb, TT, SS, DD, DD, DD,
      (long long)TT*DD, (long long)SS*DD, (long long)TT*SS, 8, 32);
  // 7) softmax + exact l_att + gated mix (XCD-affine)
  softmax_mix_kernel<<<BB*TT, 256, 0, stream>>>(dotsb, out, mask_src, steps, gates, cv);
}

// Round 8
// 196.536 us; speedup vs baseline: 1.4300x; 1.0105x over previous
//
#include <hip/hip_runtime.h>
#include <hip/hip_bf16.h>
#include <stdint.h>

typedef unsigned short ushort_t;

#define BB 8
#define SS 1024
#define TT 1024
#define DD 1024
#define INF_ 1e10f

__device__ __forceinline__ float b2f(ushort_t u){
  union { unsigned u32; float f; } x; x.u32 = ((unsigned)u) << 16; return x.f;
}
__device__ __forceinline__ ushort_t f2b(float f){
  union { float f; unsigned u; } x; x.f = f;
  unsigned r = x.u + 0x7FFFu + ((x.u >> 16) & 1u);
  return (ushort_t)(r >> 16);
}

// ---- preamble: blocks 0..2047 transpose Wq/Wk -> bf16; 2048..2055 steps;
//      blocks 2056..2119 v2[f] = sum_d Wk[d,f]*bq[d] (64 blocks, atomic-free) ----
__global__ __launch_bounds__(256) void pre_kernel(
    const float* __restrict__ Wq, const float* __restrict__ Wk,
    ushort_t* __restrict__ WqT, ushort_t* __restrict__ WkT,
    const float* __restrict__ msrc, const float* __restrict__ mtrg,
    float* __restrict__ steps, float* __restrict__ v2,
    const float* __restrict__ bq)
{
  __shared__ float tile[32][33];
  __shared__ float sh[8];
  __shared__ float shv[256];
  int blk = blockIdx.x, tid = threadIdx.x;
  if (blk < 2048){
    const float* src = (blk >= 1024) ? Wk : Wq;
    ushort_t* dst = (blk >= 1024) ? WkT : WqT;
    int q = blk & 1023;
    int tx = q & 31, ty = q >> 5;
    int c = tid & 31, r0 = tid >> 5;
    #pragma unroll
    for (int k = 0; k < 4; k++){
      int r = r0 + k*8;
      tile[r][c] = src[(size_t)(ty*32 + r)*DD + tx*32 + c];
    }
    __syncthreads();
    #pragma unroll
    for (int k = 0; k < 4; k++){
      int r = r0 + k*8;
      dst[(size_t)(tx*32 + r)*DD + ty*32 + c] = f2b(tile[c][r]);
    }
  } else if (blk < 2056){
    int b = blk - 2048;
    float a = 0.f, c = 0.f;
    for (int i = tid; i < SS; i += 256) a += msrc[b*SS + i];
    for (int i = tid; i < TT; i += 256) c += mtrg[b*TT + i];
    #pragma unroll
    for (int o = 32; o; o >>= 1){ a += __shfl_xor(a, o); c += __shfl_xor(c, o); }
    int wv = tid >> 6, ln = tid & 63;
    if (!ln){ sh[wv] = a; sh[4+wv] = c; }
    __syncthreads();
    if (!tid){
      float sa = sh[0]+sh[1]+sh[2]+sh[3];
      float sc = sh[4]+sh[5]+sh[6]+sh[7];
      steps[b] = sa / sc;
    }
  } else {
    // v2: 64 blocks x 16 cols; 16 d-groups of 64 per col, LDS reduce
    int b2 = blk - 2056;                 // 0..63
    int col = b2*16 + (tid & 15);
    int grp = tid >> 4;                  // 0..15
    float a = 0.f;
    const float* Wp = Wk + (size_t)(grp*64)*DD + col;
    for (int d = 0; d < 64; ++d) a += Wp[(size_t)d*DD] * bq[grp*64 + d];
    shv[grp*16 + (tid & 15)] = a;
    __syncthreads();
    if (grp == 0){
      float s = 0.f;
      #pragma unroll
      for (int g = 0; g < 16; g++) s += shv[g*16 + tid];
      v2[col] = s;
    }
  }
}

// ------- key rows fp32->bf16 + kw = key·wg, cv = key·v2; blocks >= BB*SS do the
//         WmT split-K reduce (4 fp32 partials -> bf16), fused to save a dispatch -------
__global__ __launch_bounds__(256) void key_convert_kernel(
    const float* __restrict__ key, const float* __restrict__ wg,
    const float* __restrict__ v2f, ushort_t* __restrict__ keyb,
    float* __restrict__ kw, float* __restrict__ cv,
    const float* __restrict__ part, ushort_t* __restrict__ wmt)
{
  __shared__ float sh[8];
  int blk = blockIdx.x;
  if (blk >= BB*SS){
    int i4 = (blk - BB*SS) * 256 + threadIdx.x;   // float4 idx, n = 1024*1024/4
    const float4* p = (const float4*)part;
    float4 a = p[i4];
    float4 b = p[i4 + 262144];
    float4 c = p[i4 + 524288];
    float4 d = p[i4 + 786432];
    ushort4 o;
    o.x = f2b(a.x + b.x + c.x + d.x);
    o.y = f2b(a.y + b.y + c.y + d.y);
    o.z = f2b(a.z + b.z + c.z + d.z);
    o.w = f2b(a.w + b.w + c.w + d.w);
    ((ushort4*)wmt)[i4] = o;
    return;
  }
  int row = blk;              // b*SS + s
  int tid = threadIdx.x, d0 = tid*4;
  float4 v = *(const float4*)(key + (size_t)row*DD + d0);
  ushort4 o; o.x=f2b(v.x); o.y=f2b(v.y); o.z=f2b(v.z); o.w=f2b(v.w);
  *(ushort4*)(keyb + (size_t)row*DD + d0) = o;
  float4 w4 = *(const float4*)(wg + d0);
  float4 u4 = *(const float4*)(v2f + d0);
  float pk = v.x*w4.x + v.y*w4.y + v.z*w4.z + v.w*w4.w;
  float pc = v.x*u4.x + v.y*u4.y + v.z*u4.z + v.w*u4.w;
  #pragma unroll
  for (int off = 32; off; off >>= 1){ pk += __shfl_xor(pk, off); pc += __shfl_xor(pc, off); }
  int wvv = tid >> 6;
  if ((tid & 63) == 0){ sh[wvv] = pk; sh[4+wvv] = pc; }
  __syncthreads();
  if (!tid){
    kw[row] = sh[0]+sh[1]+sh[2]+sh[3];
    cv[row] = sh[4]+sh[5]+sh[6]+sh[7];
  }
}

// ---- m97-style bf16 GEMM (kept for the small WmT = WkT@WqT^T split-K GEMM) ----
typedef __bf16 bf16x8 __attribute__((ext_vector_type(8)));
typedef float f32x4 __attribute__((ext_vector_type(4)));

#define CP16(g, l) __builtin_amdgcn_global_load_lds( \
    (const __attribute__((address_space(1))) void*)(g), \
    (__attribute__((address_space(3))) void*)(l), 16, 0, 0)

__global__ __launch_bounds__(256, 2) void gemm_bt_kernel(
    const ushort_t* __restrict__ A, const ushort_t* __restrict__ Bm,
    const float* __restrict__ bias, void* __restrict__ Cv,
    int M, int N, int K, int lda, int ldb,
    long long sA, long long sB, long long sC, int hasBias, int outBF16,
    int gx, int gxy)
{
  __shared__ ushort_t lA[128*32];
  __shared__ ushort_t lB[128*32];

  const int bpx = gridDim.x >> 3;
  const int lin = blockIdx.x;
  const int glob = (lin & 7) * bpx + (lin >> 3);
  const int bz = glob / gxy;
  const int rem = glob - bz * gxy;
  const int by = rem / gx;
  const int bx = rem - by * gx;

  A  += (size_t)bz * sA;
  Bm += (size_t)bz * sB;

  const int tid = threadIdx.x;
  const int wv = tid >> 6, ln = tid & 63;
  const int r4 = ln >> 2, c8 = (ln & 3) * 8;

  const ushort_t* gA0 = A  + (size_t)(by*128 + wv*32 + r4) * lda + c8;
  const ushort_t* gA1 = gA0 + (size_t)16 * lda;
  const ushort_t* gB0 = Bm + (size_t)(bx*128 + wv*32 + r4) * ldb + c8;
  const ushort_t* gB1 = gB0 + (size_t)16 * ldb;
  ushort_t* lA0 = &lA[(wv*32     ) * 32];
  ushort_t* lA1 = &lA[(wv*32 + 16) * 32];
  ushort_t* lB0 = &lB[(wv*32     ) * 32];
  ushort_t* lB1 = &lB[(wv*32 + 16) * 32];

  const int lm = ln & 15, qd = ln >> 4;
  const int wm = (wv >> 1) * 64, wn = (wv & 1) * 64;

  f32x4 acc[4][4];
  #pragma unroll
  for (int i = 0; i < 4; i++)
    #pragma unroll
    for (int j = 0; j < 4; j++) acc[i][j] = (f32x4){0.f, 0.f, 0.f, 0.f};

  for (int k0 = 0; k0 < K; k0 += 32){
    CP16(gA0, lA0); CP16(gA1, lA1); CP16(gB0, lB0); CP16(gB1, lB1);
    gA0 += 32; gA1 += 32; gB0 += 32; gB1 += 32;
    __syncthreads();
    bf16x8 af[4], bf[4];
    #pragma unroll
    for (int i = 0; i < 4; i++) af[i] = *(const bf16x8*)&lA[(wm + i*16 + lm)*32 + qd*8];
    #pragma unroll
    for (int j = 0; j < 4; j++) bf[j] = *(const bf16x8*)&lB[(wn + j*16 + lm)*32 + qd*8];
    #pragma unroll
    for (int i = 0; i < 4; i++)
      #pragma unroll
      for (int j = 0; j < 4; j++)
        acc[i][j] = __builtin_amdgcn_mfma_f32_16x16x32_bf16(af[i], bf[j], acc[i][j], 0, 0, 0);
    __syncthreads();
  }

  // C/D layout: col = lane&15, row = (lane>>4)*4 + reg   [verified m89/m91]
  const int row0 = by*128 + wm + qd*4;
  const int col0 = bx*128 + wn + lm;
  ushort_t* Cb = (ushort_t*)Cv + (size_t)bz * sC;
  float*    Cf = (float*)Cv    + (size_t)bz * sC;
  #pragma unroll
  for (int j = 0; j < 4; j++){
    int col = col0 + j*16;
    float bv = hasBias ? bias[col] : 0.f;
    #pragma unroll
    for (int i = 0; i < 4; i++)
      #pragma unroll
      for (int r = 0; r < 4; r++){
        size_t idx = (size_t)(row0 + i*16 + r) * N + col;
        float v = acc[i][j][r] + bv;
        if (outBF16) Cb[idx] = f2b(v); else Cf[idx] = v;
      }
  }
}

// ==================== 256x128-tile, BK=64, counted-vmcnt GEMM, 4Mx2N waves ====================
// R8 change (single variable): REMOVE the 3 per-phase s_barriers; keep ONE vmcnt+BAR per
// K-tile. Correctness: own-wave ds_read->MFMA fenced by lgkmcnt(0)+sched_barrier(0);
// stage-vs-read buffer reuse guarded by the tile-boundary BAR (all waves' reads of the
// to-be-overwritten buffer retired at their lgkm0 before crossing it). Waves may now
// drift within a tile -> one wave's ds_read/stage overlaps another's MFMA (m114
// implicit overlap), setprio(1) favors MFMA waves.
#define G2_STAGE_A(sel) do{ \
    ushort_t* _d = &lA3[(sel)*(256*64) + (w*8)*64]; \
    CP16(gA0, _d); \
    CP16(gA1, _d + 64*64); \
    CP16(gA2, _d + 128*64); \
    CP16(gA3, _d + 192*64); }while(0)
#define G2_STAGE_B(sel) do{ \
    ushort_t* _d = &lB3[(sel)*(128*64) + (w*8)*64]; \
    CP16(gB0, _d); \
    CP16(gB1, _d + 64*64); }while(0)
#define G2_ADV() do{ gA0+=64; gA1+=64; gA2+=64; gA3+=64; gB0+=64; gB1+=64; }while(0)
#define BAR()    asm volatile("s_barrier" ::: "memory")
#define LGKM0()  do{ asm volatile("s_waitcnt lgkmcnt(0)" ::: "memory"); \
                     __builtin_amdgcn_sched_barrier(0); }while(0)

__global__ __launch_bounds__(512, 2) void gemm256_kernel(
    const ushort_t* __restrict__ A, const ushort_t* __restrict__ Bm,
    ushort_t* __restrict__ C,
    int M, int N, int K, int lda, int ldb,
    long long sA, long long sB, long long sC, int gx, int gxy)
{
  __shared__ ushort_t lA3[3 * 256 * 64];   // 96 KB
  __shared__ ushort_t lB3[3 * 128 * 64];   // 48 KB
  (void)M;

  const int bpx = gridDim.x >> 3;
  const int lin = blockIdx.x;
  const int glob = (lin & 7) * bpx + (lin >> 3);   // XCD-chunked (grid % 8 == 0)
  const int bz = glob / gxy;
  const int rem = glob - bz * gxy;
  const int by = rem / gx;
  const int bx = rem - by * gx;

  A  += (size_t)bz * sA;
  Bm += (size_t)bz * sB;

  const int tid = threadIdx.x;
  const int w = tid >> 6, l = tid & 63;
  const int lm = l & 15, qd = l >> 4;
  const int wm = w & 3, wn = w >> 2;     // 4M x 2N wave grid

  const int srow = l >> 3;
  const int sch  = (l & 7) ^ srow;

  const ushort_t* gA0 = A + (size_t)(by*256 +       w*8 + srow) * lda + sch*8;
  const ushort_t* gA1 = gA0 + (size_t)64  * lda;
  const ushort_t* gA2 = gA0 + (size_t)128 * lda;
  const ushort_t* gA3 = gA0 + (size_t)192 * lda;
  const ushort_t* gB0 = Bm + (size_t)(bx*128 +      w*8 + srow) * ldb + sch*8;
  const ushort_t* gB1 = gB0 + (size_t)64  * ldb;

  f32x4 acc[4][4];
  #pragma unroll
  for (int i = 0; i < 4; i++)
    #pragma unroll
    for (int j = 0; j < 4; j++) acc[i][j] = (f32x4){0.f,0.f,0.f,0.f};

  // prologue: stage tiles 0 and 1 (A0[4],B0[2],A1[4],B1[2] = 12 loads)
  G2_STAGE_A(0); G2_STAGE_B(0); G2_ADV();
  G2_STAGE_A(1); G2_STAGE_B(1); G2_ADV();
  asm volatile("s_waitcnt vmcnt(6)" ::: "memory");   // tile 0 landed; tile 1 in flight
  BAR();

  const int NT = K >> 6;
  int rd = 0, st = 2;
  #pragma unroll 1
  for (int t = 0; t < NT; ++t){
    const ushort_t* sa = &lA3[rd*(256*64) + (wm*64)*64];
    const ushort_t* sb = &lB3[rd*(128*64) + (wn*64)*64];
    const bool pre = (t + 2 < NT);

    // ---------------- phase 0 : k-slot 0 (no barrier) ----------------
    {
      const int ch = qd ^ (lm & 7);
      bf16x8 af[4], bfr[4];
      #pragma unroll
      for (int i = 0; i < 4; i++) af[i]  = *(const bf16x8*)&sa[(i*16 + lm)*64 + ch*8];
      #pragma unroll
      for (int j = 0; j < 4; j++) bfr[j] = *(const bf16x8*)&sb[(j*16 + lm)*64 + ch*8];
      if (pre) G2_STAGE_A(st);
      LGKM0();
      __builtin_amdgcn_s_setprio(1);
      #pragma unroll
      for (int i = 0; i < 4; i++)
        #pragma unroll
        for (int j = 0; j < 4; j++)
          acc[i][j] = __builtin_amdgcn_mfma_f32_16x16x32_bf16(af[i], bfr[j], acc[i][j], 0, 0, 0);
      __builtin_amdgcn_s_setprio(0);
    }
    // ---------------- phase 1 : k-slot 1 (no barrier) ----------------
    {
      const int ch = (4 | qd) ^ (lm & 7);
      bf16x8 af[4], bfr[4];
      #pragma unroll
      for (int i = 0; i < 4; i++) af[i]  = *(const bf16x8*)&sa[(i*16 + lm)*64 + ch*8];
      #pragma unroll
      for (int j = 0; j < 4; j++) bfr[j] = *(const bf16x8*)&sb[(j*16 + lm)*64 + ch*8];
      if (pre) G2_STAGE_B(st);
      LGKM0();
      __builtin_amdgcn_s_setprio(1);
      #pragma unroll
      for (int i = 0; i < 4; i++)
        #pragma unroll
        for (int j = 0; j < 4; j++)
          acc[i][j] = __builtin_amdgcn_mfma_f32_16x16x32_bf16(af[i], bfr[j], acc[i][j], 0, 0, 0);
      __builtin_amdgcn_s_setprio(0);
    }
    if (pre) G2_ADV();
    if (t < NT - 1){
      // ONE sync point per K-tile: tile t+1 resident, all reads of buffer st retired.
      if (pre) asm volatile("s_waitcnt vmcnt(6)" ::: "memory");
      else     asm volatile("s_waitcnt vmcnt(0)" ::: "memory");
      BAR();
    }
    rd = (rd == 2) ? 0 : rd + 1;
    st = (st == 2) ? 0 : st + 1;
  }

  // C/D layout: col = lane&15, row = (lane>>4)*4 + reg   [verified m89/m91]
  const int row0 = by*256 + wm*64 + qd*4;
  const int col0 = bx*128 + wn*64 + lm;
  ushort_t* Cp = C + (size_t)bz * sC;
  #pragma unroll
  for (int j = 0; j < 4; j++)
    #pragma unroll
    for (int i = 0; i < 4; i++)
      #pragma unroll
      for (int r = 0; r < 4; r++)
        Cp[(size_t)(row0 + i*16 + r) * N + col0 + j*16] = f2b(acc[i][j][r]);
}

// ----- banded l_att stencil on km: qm2[t] = sum_s w[t,s]*km[b,s]; gates from kw -----
__global__ __launch_bounds__(256) void band_kernel(
    const ushort_t* __restrict__ kmb, const float* __restrict__ mask_src,
    const float* __restrict__ steps, const float* __restrict__ kw,
    const float* __restrict__ bg, ushort_t* __restrict__ qm2b,
    float* __restrict__ gates)
{
  __shared__ float shw[8][17];
  __shared__ int shslo[8];
  int bx0 = blockIdx.x;
  int bx = (bx0 & 7) * 128 + (bx0 >> 3);   // bijective: b = bx0&7 stays on its XCD
  int b = bx >> 7, t0 = (bx & 127) * 8;
  int tid = threadIdx.x;

  if (tid < 8){
    int t = t0 + tid;
    float c = steps[b] * (float)t;
    int slo = (int)ceilf(c - 8.0f);
    float w[17], m = -3e38f;
    #pragma unroll
    for (int i = 0; i < 17; i++){
      int s = slo + i;
      float l = -3e38f;
      if (s >= 0 && s < SS){
        float dd = (float)s - c;
        l = -dd*dd*(1.0f/0.3f) - INF_*(1.0f - mask_src[b*SS + s]);
      }
      w[i] = l; m = fmaxf(m, l);
    }
    float norm = 0.f, ga = 0.f;
    #pragma unroll
    for (int i = 0; i < 17; i++){
      float e = __expf(w[i] - m);
      int s = slo + i;
      if (s >= 0 && s < SS) ga += e * kw[b*SS + s]; else e = 0.f;
      w[i] = e; norm += e;
    }
    float inv = 1.0f / norm;
    #pragma unroll
    for (int i = 0; i < 17; i++) shw[tid][i] = w[i] * inv;
    shslo[tid] = slo;
    gates[b*TT + t] = 1.0f / (1.0f + __expf(-(ga*inv + bg[0])));
  }
  __syncthreads();

  int smin = shslo[0], smax = shslo[7] + 16;
  if (smin < 0) smin = 0;
  if (smax > SS-1) smax = SS-1;
  int d0 = tid * 4;
  float acc[8][4];
  #pragma unroll
  for (int t = 0; t < 8; t++){ acc[t][0]=0.f; acc[t][1]=0.f; acc[t][2]=0.f; acc[t][3]=0.f; }

  const ushort_t* kbase = kmb + ((size_t)b*SS)*DD + d0;
  for (int s = smin; s <= smax; s++){
    ushort4 kv = *(const ushort4*)(kbase + (size_t)s*DD);
    float k0 = b2f(kv.x), k1 = b2f(kv.y), k2 = b2f(kv.z), k3 = b2f(kv.w);
    #pragma unroll
    for (int t = 0; t < 8; t++){
      unsigned u = (unsigned)(s - shslo[t]);
      if (u < 17u){
        float wgt = shw[t][u];
        acc[t][0] += wgt*k0; acc[t][1] += wgt*k1; acc[t][2] += wgt*k2; acc[t][3] += wgt*k3;
      }
    }
  }
  #pragma unroll
  for (int t = 0; t < 8; t++){
    ushort4 o; o.x=f2b(acc[t][0]); o.y=f2b(acc[t][1]); o.z=f2b(acc[t][2]); o.w=f2b(acc[t][3]);
    *(ushort4*)(qm2b + ((size_t)(b*TT + t0 + t))*DD + d0) = o;
  }
}

// ------- fused softmax((dots_bf16+cv)/scale) + exact l_att + gated mix -> fp32 out -------
__device__ __forceinline__ void blkmax2(float& v1, float& v2, float* sh8){
  #pragma unroll
  for (int o = 32; o; o >>= 1){
    v1 = fmaxf(v1, __shfl_xor(v1, o));
    v2 = fmaxf(v2, __shfl_xor(v2, o));
  }
  int wv = threadIdx.x >> 6;
  if ((threadIdx.x & 63) == 0){ sh8[wv] = v1; sh8[4+wv] = v2; }
  __syncthreads();
  v1 = fmaxf(fmaxf(sh8[0], sh8[1]), fmaxf(sh8[2], sh8[3]));
  v2 = fmaxf(fmaxf(sh8[4], sh8[5]), fmaxf(sh8[6], sh8[7]));
}
__device__ __forceinline__ void blksum2(float& v1, float& v2, float* sh8){
  #pragma unroll
  for (int o = 32; o; o >>= 1){
    v1 += __shfl_xor(v1, o);
    v2 += __shfl_xor(v2, o);
  }
  int wv = threadIdx.x >> 6;
  if ((threadIdx.x & 63) == 0){ sh8[wv] = v1; sh8[4+wv] = v2; }
  __syncthreads();
  v1 = sh8[0]+sh8[1]+sh8[2]+sh8[3];
  v2 = sh8[4]+sh8[5]+sh8[6]+sh8[7];
}

__global__ __launch_bounds__(256) void softmax_mix_kernel(
    const ushort_t* __restrict__ dotsb, float* __restrict__ out,
    const float* __restrict__ mask_src, const float* __restrict__ steps,
    const float* __restrict__ gates, const float* __restrict__ cv)
{
  __shared__ float shA[8];
  __shared__ float shB[8];
  int blk0 = blockIdx.x;
  int blk = (blk0 & 7) * 1024 + (blk0 >> 3);   // bijective: b = blk0&7 stays on its XCD
  int b = blk >> 10, t = blk & 1023;
  int tid = threadIdx.x;
  int s0 = tid * 4;
  float c = steps[b] * (float)t;

  ushort4 dv = *(const ushort4*)(dotsb + (size_t)blk*SS + s0);
  float4 mv = *(const float4*)(mask_src + (size_t)b*SS + s0);
  float4 cva = *(const float4*)(cv + (size_t)b*SS + s0);
  float dvf[4] = {b2f(dv.x) + cva.x, b2f(dv.y) + cva.y, b2f(dv.z) + cva.z, b2f(dv.w) + cva.w};
  float msk[4] = {mv.x, mv.y, mv.z, mv.w};
  float dl[4], ll[4];
  float dmax = -3e38f, lmax = -3e38f;
  #pragma unroll
  for (int r = 0; r < 4; r++){
    float im = INF_ * (1.0f - msk[r]);
    dl[r] = (dvf[r] - im) * (1.0f/32.0f);          // scale = sqrt(1024) = 32
    float dd = (float)(s0 + r) - c;
    ll[r] = -dd*dd*(1.0f/0.3f) - im;
    dmax = fmaxf(dmax, dl[r]);
    lmax = fmaxf(lmax, ll[r]);
  }
  blkmax2(dmax, lmax, shA);
  float ps[4], lp[4];
  float psum = 0.f, lsum = 0.f;
  #pragma unroll
  for (int r = 0; r < 4; r++){
    ps[r] = __expf(dl[r] - dmax); psum += ps[r];
    lp[r] = __expf(ll[r] - lmax); lsum += lp[r];
  }
  blksum2(psum, lsum, shB);

  float g = gates[blk];
  float ip = (1.0f - g) / psum, il = g / lsum;
  float4 ov;
  ov.x = ps[0]*ip + lp[0]*il;
  ov.y = ps[1]*ip + lp[1]*il;
  ov.z = ps[2]*ip + lp[2]*il;
  ov.w = ps[3]*ip + lp[3]*il;
  *(float4*)(out + (size_t)blk*SS + s0) = ov;
}

extern "C" void kernel_launch(void* const* d_in, const int* in_sizes, int n_in,
                              void* d_out, int out_size, void* d_ws, size_t ws_size,
                              hipStream_t stream)
{
  const float* key      = (const float*)d_in[0];
  const float* mask_src = (const float*)d_in[1];
  const float* mask_trg = (const float*)d_in[2];
  const float* Wq       = (const float*)d_in[3];
  const float* bq       = (const float*)d_in[4];
  const float* Wk       = (const float*)d_in[5];
  const float* bk       = (const float*)d_in[6];
  const float* wg       = (const float*)d_in[7];
  const float* bg       = (const float*)d_in[8];
  float* out = (float*)d_out;   // fp32 [B,T,S] = 32 MB, written ONLY by softmax
  (void)bk;  // bk contributes only a row-constant softmax shift -> cancels

  // ws layout (~54.3 MB):
  char* ws = (char*)d_ws;
  float* steps     = (float*)ws;                         // 32 B
  float* gates     = (float*)(ws + 4096);                // 32 KB
  float* cv        = (float*)(ws + 4096 + 32768);        // 32 KB
  float* kw        = (float*)(ws + 4096 + 65536);        // 32 KB
  float* v2        = (float*)(ws + 4096 + 98304);        // 4 KB
  ushort_t* WqTb   = (ushort_t*)(ws + 131072);           // 2 MB
  ushort_t* WkTb   = WqTb + (size_t)DD*DD;               // 2 MB
  ushort_t* WmTb   = WkTb + (size_t)DD*DD;               // 2 MB
  ushort_t* keyb   = WmTb + (size_t)DD*DD;               // 16 MB
  ushort_t* kmb    = keyb + (size_t)BB*SS*DD;            // 16 MB (km; DEAD after band -> reused as dotsb)
  char* shared16   = (char*)(kmb + (size_t)BB*SS*DD);    // 16 MB: WmT partials, later qm2b
  float* wmPart    = (float*)shared16;                   // 4 x 1M fp32
  ushort_t* qm2b   = (ushort_t*)shared16;                // 16 MB (after the fused reduce)
  ushort_t* dotsb  = kmb;                                // bf16 dots in km's dead slot

  // 1) transposes + steps + v2 (64-block, atomic-free)
  pre_kernel<<<2120, 256, 0, stream>>>(Wq, Wk, WqTb, WkTb, mask_src, mask_trg, steps, v2, bq);
  // 2) WmT[f,e] = sum_d Wk[d,f] Wq[d,e] = WkT @ WqT^T, split-K=4 over d -> fp32 partials
  gemm_bt_kernel<<<256, 256, 0, stream>>>(
      WkTb, WqTb, nullptr, (void*)wmPart, DD, DD, DD/4, DD, DD,
      DD/4, DD/4, (long long)DD*DD, 0, 0, 8, 64);
  // 3) key convert + kw/cv, fused with the WmT partial reduce (blocks >= BB*SS)
  key_convert_kernel<<<BB*SS + 1024, 256, 0, stream>>>(
      key, wg, v2, keyb, kw, cv, wmPart, WmTb);
  // 4) km = keyb @ Wm   [8192 x 1024 x 1024] -> bf16
  gemm256_kernel<<<256, 512, 0, stream>>>(
      keyb, WmTb, kmb, BB*SS, DD, DD, DD, DD, 0, 0, 0, 8, 256);
  // 5) qm2 = l_att · km (banded) + gates  (XCD-affine)
  band_kernel<<<BB*TT/8, 256, 0, stream>>>(kmb, mask_src, steps, kw, bg, qm2b, gates);
  // 6) dots[b] = qm2[b] @ keyb[b]^T -> dotsb (one batch per XCD)
  gemm256_kernel<<<256, 512, 0, stream>>>(
      qm2b, keyb, dotsb, TT, SS, DD, DD, DD,
      (long long)TT*DD, (long long)SS*DD, (long long)TT*SS, 8, 32);
  // 7) softmax + exact l_att + gated mix (XCD-affine)
  softmax_mix_kernel<<<BB*TT, 256, 0, stream>>>(dotsb, out, mask_src, steps, gates, cv);
}

// Round 9
// 192.593 us; speedup vs baseline: 1.4592x; 1.0205x over previous
//
#include <hip/hip_runtime.h>
#include <hip/hip_bf16.h>
#include <stdint.h>

typedef unsigned short ushort_t;

#define BB 8
#define SS 1024
#define TT 1024
#define DD 1024
#define INF_ 1e10f

__device__ __forceinline__ float b2f(ushort_t u){
  union { unsigned u32; float f; } x; x.u32 = ((unsigned)u) << 16; return x.f;
}
__device__ __forceinline__ ushort_t f2b(float f){
  union { float f; unsigned u; } x; x.f = f;
  unsigned r = x.u + 0x7FFFu + ((x.u >> 16) & 1u);
  return (ushort_t)(r >> 16);
}

// ---- preamble: blocks 0..2047 transpose Wq/Wk -> bf16; 2048..2055 steps;
//      blocks 2056..2119 v2[f] = sum_d Wk[d,f]*bq[d] (64 blocks, atomic-free) ----
// R9: store phase writes ushort4 (8B/thread) instead of 4x scalar 2B (G13).
__global__ __launch_bounds__(256) void pre_kernel(
    const float* __restrict__ Wq, const float* __restrict__ Wk,
    ushort_t* __restrict__ WqT, ushort_t* __restrict__ WkT,
    const float* __restrict__ msrc, const float* __restrict__ mtrg,
    float* __restrict__ steps, float* __restrict__ v2,
    const float* __restrict__ bq)
{
  __shared__ float tile[32][33];
  __shared__ float sh[8];
  __shared__ float shv[256];
  int blk = blockIdx.x, tid = threadIdx.x;
  if (blk < 2048){
    const float* src = (blk >= 1024) ? Wk : Wq;
    ushort_t* dst = (blk >= 1024) ? WkT : WqT;
    int q = blk & 1023;
    int tx = q & 31, ty = q >> 5;
    int c = tid & 31, r0 = tid >> 5;
    #pragma unroll
    for (int k = 0; k < 4; k++){
      int r = r0 + k*8;
      tile[r][c] = src[(size_t)(ty*32 + r)*DD + tx*32 + c];
    }
    __syncthreads();
    // vectorized transposed store: thread (rr, cc0) writes 4 consecutive dst cols.
    // LDS read tile[cc0+i][rr]: bank = (4*(tid&7) + i + (tid>>3)) % 32 -> <=2-way (free).
    int rr = tid >> 3, cc0 = (tid & 7) * 4;
    ushort4 o;
    o.x = f2b(tile[cc0+0][rr]);
    o.y = f2b(tile[cc0+1][rr]);
    o.z = f2b(tile[cc0+2][rr]);
    o.w = f2b(tile[cc0+3][rr]);
    *(ushort4*)(dst + (size_t)(tx*32 + rr)*DD + ty*32 + cc0) = o;
  } else if (blk < 2056){
    int b = blk - 2048;
    float a = 0.f, c = 0.f;
    for (int i = tid; i < SS; i += 256) a += msrc[b*SS + i];
    for (int i = tid; i < TT; i += 256) c += mtrg[b*TT + i];
    #pragma unroll
    for (int o = 32; o; o >>= 1){ a += __shfl_xor(a, o); c += __shfl_xor(c, o); }
    int wv = tid >> 6, ln = tid & 63;
    if (!ln){ sh[wv] = a; sh[4+wv] = c; }
    __syncthreads();
    if (!tid){
      float sa = sh[0]+sh[1]+sh[2]+sh[3];
      float sc = sh[4]+sh[5]+sh[6]+sh[7];
      steps[b] = sa / sc;
    }
  } else {
    // v2: 64 blocks x 16 cols; 16 d-groups of 64 per col, LDS reduce
    int b2 = blk - 2056;                 // 0..63
    int col = b2*16 + (tid & 15);
    int grp = tid >> 4;                  // 0..15
    float a = 0.f;
    const float* Wp = Wk + (size_t)(grp*64)*DD + col;
    for (int d = 0; d < 64; ++d) a += Wp[(size_t)d*DD] * bq[grp*64 + d];
    shv[grp*16 + (tid & 15)] = a;
    __syncthreads();
    if (grp == 0){
      float s = 0.f;
      #pragma unroll
      for (int g = 0; g < 16; g++) s += shv[g*16 + tid];
      v2[col] = s;
    }
  }
}

// ------- R9: wave-per-row key convert (no LDS, no barriers) + folded WmT reduce -------
// blocks 0..2047: 4 key rows each (1 wave/row); blocks 2048..2303: WmT reduce x4 groups.
__global__ __launch_bounds__(256) void key_convert_kernel(
    const float* __restrict__ key, const float* __restrict__ wg,
    const float* __restrict__ v2f, ushort_t* __restrict__ keyb,
    float* __restrict__ kw, float* __restrict__ cv,
    const float* __restrict__ part, ushort_t* __restrict__ wmt)
{
  int blk = blockIdx.x;
  int tid = threadIdx.x;
  if (blk >= 2048){
    const float4* p = (const float4*)part;
    int base = (blk - 2048) * 1024 + tid;
    #pragma unroll
    for (int g = 0; g < 4; g++){
      int i4 = base + g*256;
      float4 a = p[i4];
      float4 b = p[i4 + 262144];
      float4 c = p[i4 + 524288];
      float4 d = p[i4 + 786432];
      ushort4 o;
      o.x = f2b(a.x + b.x + c.x + d.x);
      o.y = f2b(a.y + b.y + c.y + d.y);
      o.z = f2b(a.z + b.z + c.z + d.z);
      o.w = f2b(a.w + b.w + c.w + d.w);
      ((ushort4*)wmt)[i4] = o;
    }
    return;
  }
  int wv = tid >> 6, l = tid & 63;
  int row = blk*4 + wv;
  const float* kp = key + (size_t)row*DD;
  float pk = 0.f, pc = 0.f;
  #pragma unroll
  for (int i = 0; i < 4; i++){
    int d = i*256 + l*4;                 // coalesced: lanes consecutive float4s
    float4 v = *(const float4*)(kp + d);
    float4 w4 = *(const float4*)(wg + d);
    float4 u4 = *(const float4*)(v2f + d);
    ushort4 o; o.x=f2b(v.x); o.y=f2b(v.y); o.z=f2b(v.z); o.w=f2b(v.w);
    *(ushort4*)(keyb + (size_t)row*DD + d) = o;
    pk += v.x*w4.x + v.y*w4.y + v.z*w4.z + v.w*w4.w;
    pc += v.x*u4.x + v.y*u4.y + v.z*u4.z + v.w*u4.w;
  }
  #pragma unroll
  for (int off = 32; off; off >>= 1){ pk += __shfl_xor(pk, off); pc += __shfl_xor(pc, off); }
  if (!l){ kw[row] = pk; cv[row] = pc; }
}

// ---- m97-style bf16 GEMM (kept for the small WmT = WkT@WqT^T split-K GEMM) ----
typedef __bf16 bf16x8 __attribute__((ext_vector_type(8)));
typedef float f32x4 __attribute__((ext_vector_type(4)));

#define CP16(g, l) __builtin_amdgcn_global_load_lds( \
    (const __attribute__((address_space(1))) void*)(g), \
    (__attribute__((address_space(3))) void*)(l), 16, 0, 0)

__global__ __launch_bounds__(256, 2) void gemm_bt_kernel(
    const ushort_t* __restrict__ A, const ushort_t* __restrict__ Bm,
    const float* __restrict__ bias, void* __restrict__ Cv,
    int M, int N, int K, int lda, int ldb,
    long long sA, long long sB, long long sC, int hasBias, int outBF16,
    int gx, int gxy)
{
  __shared__ ushort_t lA[128*32];
  __shared__ ushort_t lB[128*32];

  const int bpx = gridDim.x >> 3;
  const int lin = blockIdx.x;
  const int glob = (lin & 7) * bpx + (lin >> 3);
  const int bz = glob / gxy;
  const int rem = glob - bz * gxy;
  const int by = rem / gx;
  const int bx = rem - by * gx;

  A  += (size_t)bz * sA;
  Bm += (size_t)bz * sB;

  const int tid = threadIdx.x;
  const int wv = tid >> 6, ln = tid & 63;
  const int r4 = ln >> 2, c8 = (ln & 3) * 8;

  const ushort_t* gA0 = A  + (size_t)(by*128 + wv*32 + r4) * lda + c8;
  const ushort_t* gA1 = gA0 + (size_t)16 * lda;
  const ushort_t* gB0 = Bm + (size_t)(bx*128 + wv*32 + r4) * ldb + c8;
  const ushort_t* gB1 = gB0 + (size_t)16 * ldb;
  ushort_t* lA0 = &lA[(wv*32     ) * 32];
  ushort_t* lA1 = &lA[(wv*32 + 16) * 32];
  ushort_t* lB0 = &lB[(wv*32     ) * 32];
  ushort_t* lB1 = &lB[(wv*32 + 16) * 32];

  const int lm = ln & 15, qd = ln >> 4;
  const int wm = (wv >> 1) * 64, wn = (wv & 1) * 64;

  f32x4 acc[4][4];
  #pragma unroll
  for (int i = 0; i < 4; i++)
    #pragma unroll
    for (int j = 0; j < 4; j++) acc[i][j] = (f32x4){0.f, 0.f, 0.f, 0.f};

  for (int k0 = 0; k0 < K; k0 += 32){
    CP16(gA0, lA0); CP16(gA1, lA1); CP16(gB0, lB0); CP16(gB1, lB1);
    gA0 += 32; gA1 += 32; gB0 += 32; gB1 += 32;
    __syncthreads();
    bf16x8 af[4], bf[4];
    #pragma unroll
    for (int i = 0; i < 4; i++) af[i] = *(const bf16x8*)&lA[(wm + i*16 + lm)*32 + qd*8];
    #pragma unroll
    for (int j = 0; j < 4; j++) bf[j] = *(const bf16x8*)&lB[(wn + j*16 + lm)*32 + qd*8];
    #pragma unroll
    for (int i = 0; i < 4; i++)
      #pragma unroll
      for (int j = 0; j < 4; j++)
        acc[i][j] = __builtin_amdgcn_mfma_f32_16x16x32_bf16(af[i], bf[j], acc[i][j], 0, 0, 0);
    __syncthreads();
  }

  // C/D layout: col = lane&15, row = (lane>>4)*4 + reg   [verified m89/m91]
  const int row0 = by*128 + wm + qd*4;
  const int col0 = bx*128 + wn + lm;
  ushort_t* Cb = (ushort_t*)Cv + (size_t)bz * sC;
  float*    Cf = (float*)Cv    + (size_t)bz * sC;
  #pragma unroll
  for (int j = 0; j < 4; j++){
    int col = col0 + j*16;
    float bv = hasBias ? bias[col] : 0.f;
    #pragma unroll
    for (int i = 0; i < 4; i++)
      #pragma unroll
      for (int r = 0; r < 4; r++){
        size_t idx = (size_t)(row0 + i*16 + r) * N + col;
        float v = acc[i][j][r] + bv;
        if (outBF16) Cb[idx] = f2b(v); else Cf[idx] = v;
      }
  }
}

// ==================== 256x128-tile, BK=64, counted-vmcnt GEMM, 4Mx2N waves ====================
// (verified R8 kernel — unchanged: one vmcnt+BAR per K-tile, per-wave lgkm0 fences)
#define G2_STAGE_A(sel) do{ \
    ushort_t* _d = &lA3[(sel)*(256*64) + (w*8)*64]; \
    CP16(gA0, _d); \
    CP16(gA1, _d + 64*64); \
    CP16(gA2, _d + 128*64); \
    CP16(gA3, _d + 192*64); }while(0)
#define G2_STAGE_B(sel) do{ \
    ushort_t* _d = &lB3[(sel)*(128*64) + (w*8)*64]; \
    CP16(gB0, _d); \
    CP16(gB1, _d + 64*64); }while(0)
#define G2_ADV() do{ gA0+=64; gA1+=64; gA2+=64; gA3+=64; gB0+=64; gB1+=64; }while(0)
#define BAR()    asm volatile("s_barrier" ::: "memory")
#define LGKM0()  do{ asm volatile("s_waitcnt lgkmcnt(0)" ::: "memory"); \
                     __builtin_amdgcn_sched_barrier(0); }while(0)

__global__ __launch_bounds__(512, 2) void gemm256_kernel(
    const ushort_t* __restrict__ A, const ushort_t* __restrict__ Bm,
    ushort_t* __restrict__ C,
    int M, int N, int K, int lda, int ldb,
    long long sA, long long sB, long long sC, int gx, int gxy)
{
  __shared__ ushort_t lA3[3 * 256 * 64];   // 96 KB
  __shared__ ushort_t lB3[3 * 128 * 64];   // 48 KB
  (void)M;

  const int bpx = gridDim.x >> 3;
  const int lin = blockIdx.x;
  const int glob = (lin & 7) * bpx + (lin >> 3);   // XCD-chunked (grid % 8 == 0)
  const int bz = glob / gxy;
  const int rem = glob - bz * gxy;
  const int by = rem / gx;
  const int bx = rem - by * gx;

  A  += (size_t)bz * sA;
  Bm += (size_t)bz * sB;

  const int tid = threadIdx.x;
  const int w = tid >> 6, l = tid & 63;
  const int lm = l & 15, qd = l >> 4;
  const int wm = w & 3, wn = w >> 2;     // 4M x 2N wave grid

  const int srow = l >> 3;
  const int sch  = (l & 7) ^ srow;

  const ushort_t* gA0 = A + (size_t)(by*256 +       w*8 + srow) * lda + sch*8;
  const ushort_t* gA1 = gA0 + (size_t)64  * lda;
  const ushort_t* gA2 = gA0 + (size_t)128 * lda;
  const ushort_t* gA3 = gA0 + (size_t)192 * lda;
  const ushort_t* gB0 = Bm + (size_t)(bx*128 +      w*8 + srow) * ldb + sch*8;
  const ushort_t* gB1 = gB0 + (size_t)64  * ldb;

  f32x4 acc[4][4];
  #pragma unroll
  for (int i = 0; i < 4; i++)
    #pragma unroll
    for (int j = 0; j < 4; j++) acc[i][j] = (f32x4){0.f,0.f,0.f,0.f};

  // prologue: stage tiles 0 and 1 (A0[4],B0[2],A1[4],B1[2] = 12 loads)
  G2_STAGE_A(0); G2_STAGE_B(0); G2_ADV();
  G2_STAGE_A(1); G2_STAGE_B(1); G2_ADV();
  asm volatile("s_waitcnt vmcnt(6)" ::: "memory");   // tile 0 landed; tile 1 in flight
  BAR();

  const int NT = K >> 6;
  int rd = 0, st = 2;
  #pragma unroll 1
  for (int t = 0; t < NT; ++t){
    const ushort_t* sa = &lA3[rd*(256*64) + (wm*64)*64];
    const ushort_t* sb = &lB3[rd*(128*64) + (wn*64)*64];
    const bool pre = (t + 2 < NT);

    // ---------------- phase 0 : k-slot 0 (no barrier) ----------------
    {
      const int ch = qd ^ (lm & 7);
      bf16x8 af[4], bfr[4];
      #pragma unroll
      for (int i = 0; i < 4; i++) af[i]  = *(const bf16x8*)&sa[(i*16 + lm)*64 + ch*8];
      #pragma unroll
      for (int j = 0; j < 4; j++) bfr[j] = *(const bf16x8*)&sb[(j*16 + lm)*64 + ch*8];
      if (pre) G2_STAGE_A(st);
      LGKM0();
      __builtin_amdgcn_s_setprio(1);
      #pragma unroll
      for (int i = 0; i < 4; i++)
        #pragma unroll
        for (int j = 0; j < 4; j++)
          acc[i][j] = __builtin_amdgcn_mfma_f32_16x16x32_bf16(af[i], bfr[j], acc[i][j], 0, 0, 0);
      __builtin_amdgcn_s_setprio(0);
    }
    // ---------------- phase 1 : k-slot 1 (no barrier) ----------------
    {
      const int ch = (4 | qd) ^ (lm & 7);
      bf16x8 af[4], bfr[4];
      #pragma unroll
      for (int i = 0; i < 4; i++) af[i]  = *(const bf16x8*)&sa[(i*16 + lm)*64 + ch*8];
      #pragma unroll
      for (int j = 0; j < 4; j++) bfr[j] = *(const bf16x8*)&sb[(j*16 + lm)*64 + ch*8];
      if (pre) G2_STAGE_B(st);
      LGKM0();
      __builtin_amdgcn_s_setprio(1);
      #pragma unroll
      for (int i = 0; i < 4; i++)
        #pragma unroll
        for (int j = 0; j < 4; j++)
          acc[i][j] = __builtin_amdgcn_mfma_f32_16x16x32_bf16(af[i], bfr[j], acc[i][j], 0, 0, 0);
      __builtin_amdgcn_s_setprio(0);
    }
    if (pre) G2_ADV();
    if (t < NT - 1){
      // ONE sync point per K-tile: tile t+1 resident, all reads of buffer st retired.
      if (pre) asm volatile("s_waitcnt vmcnt(6)" ::: "memory");
      else     asm volatile("s_waitcnt vmcnt(0)" ::: "memory");
      BAR();
    }
    rd = (rd == 2) ? 0 : rd + 1;
    st = (st == 2) ? 0 : st + 1;
  }

  // C/D layout: col = lane&15, row = (lane>>4)*4 + reg   [verified m89/m91]
  const int row0 = by*256 + wm*64 + qd*4;
  const int col0 = bx*128 + wn*64 + lm;
  ushort_t* Cp = C + (size_t)bz * sC;
  #pragma unroll
  for (int j = 0; j < 4; j++)
    #pragma unroll
    for (int i = 0; i < 4; i++)
      #pragma unroll
      for (int r = 0; r < 4; r++)
        Cp[(size_t)(row0 + i*16 + r) * N + col0 + j*16] = f2b(acc[i][j][r]);
}

// ----- banded l_att stencil on km: qm2[t] = sum_s w[t,s]*km[b,s]; gates from kw -----
__global__ __launch_bounds__(256) void band_kernel(
    const ushort_t* __restrict__ kmb, const float* __restrict__ mask_src,
    const float* __restrict__ steps, const float* __restrict__ kw,
    const float* __restrict__ bg, ushort_t* __restrict__ qm2b,
    float* __restrict__ gates)
{
  __shared__ float shw[8][17];
  __shared__ int shslo[8];
  int bx0 = blockIdx.x;
  int bx = (bx0 & 7) * 128 + (bx0 >> 3);   // bijective: b = bx0&7 stays on its XCD
  int b = bx >> 7, t0 = (bx & 127) * 8;
  int tid = threadIdx.x;

  if (tid < 8){
    int t = t0 + tid;
    float c = steps[b] * (float)t;
    int slo = (int)ceilf(c - 8.0f);
    float w[17], m = -3e38f;
    #pragma unroll
    for (int i = 0; i < 17; i++){
      int s = slo + i;
      float l = -3e38f;
      if (s >= 0 && s < SS){
        float dd = (float)s - c;
        l = -dd*dd*(1.0f/0.3f) - INF_*(1.0f - mask_src[b*SS + s]);
      }
      w[i] = l; m = fmaxf(m, l);
    }
    float norm = 0.f, ga = 0.f;
    #pragma unroll
    for (int i = 0; i < 17; i++){
      float e = __expf(w[i] - m);
      int s = slo + i;
      if (s >= 0 && s < SS) ga += e * kw[b*SS + s]; else e = 0.f;
      w[i] = e; norm += e;
    }
    float inv = 1.0f / norm;
    #pragma unroll
    for (int i = 0; i < 17; i++) shw[tid][i] = w[i] * inv;
    shslo[tid] = slo;
    gates[b*TT + t] = 1.0f / (1.0f + __expf(-(ga*inv + bg[0])));
  }
  __syncthreads();

  int smin = shslo[0], smax = shslo[7] + 16;
  if (smin < 0) smin = 0;
  if (smax > SS-1) smax = SS-1;
  int d0 = tid * 4;
  float acc[8][4];
  #pragma unroll
  for (int t = 0; t < 8; t++){ acc[t][0]=0.f; acc[t][1]=0.f; acc[t][2]=0.f; acc[t][3]=0.f; }

  const ushort_t* kbase = kmb + ((size_t)b*SS)*DD + d0;
  for (int s = smin; s <= smax; s++){
    ushort4 kv = *(const ushort4*)(kbase + (size_t)s*DD);
    float k0 = b2f(kv.x), k1 = b2f(kv.y), k2 = b2f(kv.z), k3 = b2f(kv.w);
    #pragma unroll
    for (int t = 0; t < 8; t++){
      unsigned u = (unsigned)(s - shslo[t]);
      if (u < 17u){
        float wgt = shw[t][u];
        acc[t][0] += wgt*k0; acc[t][1] += wgt*k1; acc[t][2] += wgt*k2; acc[t][3] += wgt*k3;
      }
    }
  }
  #pragma unroll
  for (int t = 0; t < 8; t++){
    ushort4 o; o.x=f2b(acc[t][0]); o.y=f2b(acc[t][1]); o.z=f2b(acc[t][2]); o.w=f2b(acc[t][3]);
    *(ushort4*)(qm2b + ((size_t)(b*TT + t0 + t))*DD + d0) = o;
  }
}

// ------- R9: wave-per-row softmax+mix (no LDS, no barriers). 4 rows/block, 2048 blocks.
// XCD affinity preserved: batch b = blk0&7 (dots batch b was produced on XCD b).
__global__ __launch_bounds__(256) void softmax_mix_kernel(
    const ushort_t* __restrict__ dotsb, float* __restrict__ out,
    const float* __restrict__ mask_src, const float* __restrict__ steps,
    const float* __restrict__ gates, const float* __restrict__ cv)
{
  int blk0 = blockIdx.x;                 // 0..2047
  int tid = threadIdx.x, wv = tid >> 6, l = tid & 63;
  int b = blk0 & 7;
  int t = (blk0 >> 3)*4 + wv;
  int row = b*TT + t;
  float c = steps[b] * (float)t;
  float g = gates[row];

  const ushort_t* dp = dotsb + (size_t)row*SS;
  const float* mp = mask_src + (size_t)b*SS;
  const float* cp = cv + (size_t)b*SS;

  float dl[16], ll[16];
  float dmax = -3e38f, lmax = -3e38f;
  #pragma unroll
  for (int i = 0; i < 4; i++){
    int s0 = i*256 + l*4;                // coalesced across the wave
    ushort4 dv = *(const ushort4*)(dp + s0);
    float4 mv = *(const float4*)(mp + s0);
    float4 cva = *(const float4*)(cp + s0);
    float dvf[4] = {b2f(dv.x)+cva.x, b2f(dv.y)+cva.y, b2f(dv.z)+cva.z, b2f(dv.w)+cva.w};
    float msk[4] = {mv.x, mv.y, mv.z, mv.w};
    #pragma unroll
    for (int r = 0; r < 4; r++){
      float im = INF_ * (1.0f - msk[r]);
      dl[i*4+r] = (dvf[r] - im) * (1.0f/32.0f);
      float dd = (float)(s0 + r) - c;
      ll[i*4+r] = -dd*dd*(1.0f/0.3f) - im;
      dmax = fmaxf(dmax, dl[i*4+r]);
      lmax = fmaxf(lmax, ll[i*4+r]);
    }
  }
  #pragma unroll
  for (int o = 32; o; o >>= 1){
    dmax = fmaxf(dmax, __shfl_xor(dmax, o));
    lmax = fmaxf(lmax, __shfl_xor(lmax, o));
  }
  float psum = 0.f, lsum = 0.f;
  #pragma unroll
  for (int j = 0; j < 16; j++){
    dl[j] = __expf(dl[j] - dmax); psum += dl[j];
    ll[j] = __expf(ll[j] - lmax); lsum += ll[j];
  }
  #pragma unroll
  for (int o = 32; o; o >>= 1){
    psum += __shfl_xor(psum, o);
    lsum += __shfl_xor(lsum, o);
  }
  float ip = (1.0f - g) / psum, il = g / lsum;
  #pragma unroll
  for (int i = 0; i < 4; i++){
    int s0 = i*256 + l*4;
    float4 ov;
    ov.x = dl[i*4+0]*ip + ll[i*4+0]*il;
    ov.y = dl[i*4+1]*ip + ll[i*4+1]*il;
    ov.z = dl[i*4+2]*ip + ll[i*4+2]*il;
    ov.w = dl[i*4+3]*ip + ll[i*4+3]*il;
    *(float4*)(out + (size_t)row*SS + s0) = ov;
  }
}

extern "C" void kernel_launch(void* const* d_in, const int* in_sizes, int n_in,
                              void* d_out, int out_size, void* d_ws, size_t ws_size,
                              hipStream_t stream)
{
  const float* key      = (const float*)d_in[0];
  const float* mask_src = (const float*)d_in[1];
  const float* mask_trg = (const float*)d_in[2];
  const float* Wq       = (const float*)d_in[3];
  const float* bq       = (const float*)d_in[4];
  const float* Wk       = (const float*)d_in[5];
  const float* bk       = (const float*)d_in[6];
  const float* wg       = (const float*)d_in[7];
  const float* bg       = (const float*)d_in[8];
  float* out = (float*)d_out;   // fp32 [B,T,S] = 32 MB, written ONLY by softmax
  (void)bk;  // bk contributes only a row-constant softmax shift -> cancels

  // ws layout (~54.3 MB):
  char* ws = (char*)d_ws;
  float* steps     = (float*)ws;                         // 32 B
  float* gates     = (float*)(ws + 4096);                // 32 KB
  float* cv        = (float*)(ws + 4096 + 32768);        // 32 KB
  float* kw        = (float*)(ws + 4096 + 65536);        // 32 KB
  float* v2        = (float*)(ws + 4096 + 98304);        // 4 KB
  ushort_t* WqTb   = (ushort_t*)(ws + 131072);           // 2 MB
  ushort_t* WkTb   = WqTb + (size_t)DD*DD;               // 2 MB
  ushort_t* WmTb   = WkTb + (size_t)DD*DD;               // 2 MB
  ushort_t* keyb   = WmTb + (size_t)DD*DD;               // 16 MB
  ushort_t* kmb    = keyb + (size_t)BB*SS*DD;            // 16 MB (km; DEAD after band -> reused as dotsb)
  char* shared16   = (char*)(kmb + (size_t)BB*SS*DD);    // 16 MB: WmT partials, later qm2b
  float* wmPart    = (float*)shared16;                   // 4 x 1M fp32
  ushort_t* qm2b   = (ushort_t*)shared16;                // 16 MB (after the fused reduce)
  ushort_t* dotsb  = kmb;                                // bf16 dots in km's dead slot

  // 1) transposes + steps + v2 (64-block, atomic-free)
  pre_kernel<<<2120, 256, 0, stream>>>(Wq, Wk, WqTb, WkTb, mask_src, mask_trg, steps, v2, bq);
  // 2) WmT[f,e] = sum_d Wk[d,f] Wq[d,e] = WkT @ WqT^T, split-K=4 over d -> fp32 partials
  gemm_bt_kernel<<<256, 256, 0, stream>>>(
      WkTb, WqTb, nullptr, (void*)wmPart, DD, DD, DD/4, DD, DD,
      DD/4, DD/4, (long long)DD*DD, 0, 0, 8, 64);
  // 3) key convert (wave-per-row) + folded WmT partial reduce (blocks >= 2048)
  key_convert_kernel<<<2048 + 256, 256, 0, stream>>>(
      key, wg, v2, keyb, kw, cv, wmPart, WmTb);
  // 4) km = keyb @ Wm   [8192 x 1024 x 1024] -> bf16
  gemm256_kernel<<<256, 512, 0, stream>>>(
      keyb, WmTb, kmb, BB*SS, DD, DD, DD, DD, 0, 0, 0, 8, 256);
  // 5) qm2 = l_att · km (banded) + gates  (XCD-affine)
  band_kernel<<<BB*TT/8, 256, 0, stream>>>(kmb, mask_src, steps, kw, bg, qm2b, gates);
  // 6) dots[b] = qm2[b] @ keyb[b]^T -> dotsb (one batch per XCD)
  gemm256_kernel<<<256, 512, 0, stream>>>(
      qm2b, keyb, dotsb, TT, SS, DD, DD, DD,
      (long long)TT*DD, (long long)SS*DD, (long long)TT*SS, 8, 32);
  // 7) softmax + exact l_att + gated mix (wave-per-row, XCD-affine)
  softmax_mix_kernel<<<2048, 256, 0, stream>>>(dotsb, out, mask_src, steps, gates, cv);
}

// Round 10
// 192.434 us; speedup vs baseline: 1.4604x; 1.0008x over previous
//
#include <hip/hip_runtime.h>
#include <hip/hip_bf16.h>
#include <stdint.h>

typedef unsigned short ushort_t;

#define BB 8
#define SS 1024
#define TT 1024
#define DD 1024
#define INF_ 1e10f

__device__ __forceinline__ float b2f(ushort_t u){
  union { unsigned u32; float f; } x; x.u32 = ((unsigned)u) << 16; return x.f;
}
__device__ __forceinline__ ushort_t f2b(float f){
  union { float f; unsigned u; } x; x.f = f;
  unsigned r = x.u + 0x7FFFu + ((x.u >> 16) & 1u);
  return (ushort_t)(r >> 16);
}

// ---- preamble: blocks 0..2047 transpose Wq/Wk -> bf16; 2048..2055 steps;
//      blocks 2056..2119 v2[f] = sum_d Wk[d,f]*bq[d] (64 blocks, atomic-free) ----
__global__ __launch_bounds__(256) void pre_kernel(
    const float* __restrict__ Wq, const float* __restrict__ Wk,
    ushort_t* __restrict__ WqT, ushort_t* __restrict__ WkT,
    const float* __restrict__ msrc, const float* __restrict__ mtrg,
    float* __restrict__ steps, float* __restrict__ v2,
    const float* __restrict__ bq)
{
  __shared__ float tile[32][33];
  __shared__ float sh[8];
  __shared__ float shv[256];
  int blk = blockIdx.x, tid = threadIdx.x;
  if (blk < 2048){
    const float* src = (blk >= 1024) ? Wk : Wq;
    ushort_t* dst = (blk >= 1024) ? WkT : WqT;
    int q = blk & 1023;
    int tx = q & 31, ty = q >> 5;
    int c = tid & 31, r0 = tid >> 5;
    #pragma unroll
    for (int k = 0; k < 4; k++){
      int r = r0 + k*8;
      tile[r][c] = src[(size_t)(ty*32 + r)*DD + tx*32 + c];
    }
    __syncthreads();
    // vectorized transposed store: thread (rr, cc0) writes 4 consecutive dst cols.
    int rr = tid >> 3, cc0 = (tid & 7) * 4;
    ushort4 o;
    o.x = f2b(tile[cc0+0][rr]);
    o.y = f2b(tile[cc0+1][rr]);
    o.z = f2b(tile[cc0+2][rr]);
    o.w = f2b(tile[cc0+3][rr]);
    *(ushort4*)(dst + (size_t)(tx*32 + rr)*DD + ty*32 + cc0) = o;
  } else if (blk < 2056){
    int b = blk - 2048;
    float a = 0.f, c = 0.f;
    for (int i = tid; i < SS; i += 256) a += msrc[b*SS + i];
    for (int i = tid; i < TT; i += 256) c += mtrg[b*TT + i];
    #pragma unroll
    for (int o = 32; o; o >>= 1){ a += __shfl_xor(a, o); c += __shfl_xor(c, o); }
    int wv = tid >> 6, ln = tid & 63;
    if (!ln){ sh[wv] = a; sh[4+wv] = c; }
    __syncthreads();
    if (!tid){
      float sa = sh[0]+sh[1]+sh[2]+sh[3];
      float sc = sh[4]+sh[5]+sh[6]+sh[7];
      steps[b] = sa / sc;
    }
  } else {
    // v2: 64 blocks x 16 cols; 16 d-groups of 64 per col, LDS reduce
    int b2 = blk - 2056;                 // 0..63
    int col = b2*16 + (tid & 15);
    int grp = tid >> 4;                  // 0..15
    float a = 0.f;
    const float* Wp = Wk + (size_t)(grp*64)*DD + col;
    for (int d = 0; d < 64; ++d) a += Wp[(size_t)d*DD] * bq[grp*64 + d];
    shv[grp*16 + (tid & 15)] = a;
    __syncthreads();
    if (grp == 0){
      float s = 0.f;
      #pragma unroll
      for (int g = 0; g < 16; g++) s += shv[g*16 + tid];
      v2[col] = s;
    }
  }
}

// ------- wave-per-row key convert (no LDS, no barriers) + folded WmT reduce -------
__global__ __launch_bounds__(256) void key_convert_kernel(
    const float* __restrict__ key, const float* __restrict__ wg,
    const float* __restrict__ v2f, ushort_t* __restrict__ keyb,
    float* __restrict__ kw, float* __restrict__ cv,
    const float* __restrict__ part, ushort_t* __restrict__ wmt)
{
  int blk = blockIdx.x;
  int tid = threadIdx.x;
  if (blk >= 2048){
    const float4* p = (const float4*)part;
    int base = (blk - 2048) * 1024 + tid;
    #pragma unroll
    for (int g = 0; g < 4; g++){
      int i4 = base + g*256;
      float4 a = p[i4];
      float4 b = p[i4 + 262144];
      float4 c = p[i4 + 524288];
      float4 d = p[i4 + 786432];
      ushort4 o;
      o.x = f2b(a.x + b.x + c.x + d.x);
      o.y = f2b(a.y + b.y + c.y + d.y);
      o.z = f2b(a.z + b.z + c.z + d.z);
      o.w = f2b(a.w + b.w + c.w + d.w);
      ((ushort4*)wmt)[i4] = o;
    }
    return;
  }
  int wv = tid >> 6, l = tid & 63;
  int row = blk*4 + wv;
  const float* kp = key + (size_t)row*DD;
  float pk = 0.f, pc = 0.f;
  #pragma unroll
  for (int i = 0; i < 4; i++){
    int d = i*256 + l*4;                 // coalesced: lanes consecutive float4s
    float4 v = *(const float4*)(kp + d);
    float4 w4 = *(const float4*)(wg + d);
    float4 u4 = *(const float4*)(v2f + d);
    ushort4 o; o.x=f2b(v.x); o.y=f2b(v.y); o.z=f2b(v.z); o.w=f2b(v.w);
    *(ushort4*)(keyb + (size_t)row*DD + d) = o;
    pk += v.x*w4.x + v.y*w4.y + v.z*w4.z + v.w*w4.w;
    pc += v.x*u4.x + v.y*u4.y + v.z*u4.z + v.w*u4.w;
  }
  #pragma unroll
  for (int off = 32; off; off >>= 1){ pk += __shfl_xor(pk, off); pc += __shfl_xor(pc, off); }
  if (!l){ kw[row] = pk; cv[row] = pc; }
}

// ---- m97-style bf16 GEMM (kept for the small WmT = WkT@WqT^T split-K GEMM) ----
typedef __bf16 bf16x8 __attribute__((ext_vector_type(8)));
typedef float f32x4 __attribute__((ext_vector_type(4)));

#define CP16(g, l) __builtin_amdgcn_global_load_lds( \
    (const __attribute__((address_space(1))) void*)(g), \
    (__attribute__((address_space(3))) void*)(l), 16, 0, 0)

__global__ __launch_bounds__(256, 2) void gemm_bt_kernel(
    const ushort_t* __restrict__ A, const ushort_t* __restrict__ Bm,
    const float* __restrict__ bias, void* __restrict__ Cv,
    int M, int N, int K, int lda, int ldb,
    long long sA, long long sB, long long sC, int hasBias, int outBF16,
    int gx, int gxy)
{
  __shared__ ushort_t lA[128*32];
  __shared__ ushort_t lB[128*32];

  const int bpx = gridDim.x >> 3;
  const int lin = blockIdx.x;
  const int glob = (lin & 7) * bpx + (lin >> 3);
  const int bz = glob / gxy;
  const int rem = glob - bz * gxy;
  const int by = rem / gx;
  const int bx = rem - by * gx;

  A  += (size_t)bz * sA;
  Bm += (size_t)bz * sB;

  const int tid = threadIdx.x;
  const int wv = tid >> 6, ln = tid & 63;
  const int r4 = ln >> 2, c8 = (ln & 3) * 8;

  const ushort_t* gA0 = A  + (size_t)(by*128 + wv*32 + r4) * lda + c8;
  const ushort_t* gA1 = gA0 + (size_t)16 * lda;
  const ushort_t* gB0 = Bm + (size_t)(bx*128 + wv*32 + r4) * ldb + c8;
  const ushort_t* gB1 = gB0 + (size_t)16 * ldb;
  ushort_t* lA0 = &lA[(wv*32     ) * 32];
  ushort_t* lA1 = &lA[(wv*32 + 16) * 32];
  ushort_t* lB0 = &lB[(wv*32     ) * 32];
  ushort_t* lB1 = &lB[(wv*32 + 16) * 32];

  const int lm = ln & 15, qd = ln >> 4;
  const int wm = (wv >> 1) * 64, wn = (wv & 1) * 64;

  f32x4 acc[4][4];
  #pragma unroll
  for (int i = 0; i < 4; i++)
    #pragma unroll
    for (int j = 0; j < 4; j++) acc[i][j] = (f32x4){0.f, 0.f, 0.f, 0.f};

  for (int k0 = 0; k0 < K; k0 += 32){
    CP16(gA0, lA0); CP16(gA1, lA1); CP16(gB0, lB0); CP16(gB1, lB1);
    gA0 += 32; gA1 += 32; gB0 += 32; gB1 += 32;
    __syncthreads();
    bf16x8 af[4], bf[4];
    #pragma unroll
    for (int i = 0; i < 4; i++) af[i] = *(const bf16x8*)&lA[(wm + i*16 + lm)*32 + qd*8];
    #pragma unroll
    for (int j = 0; j < 4; j++) bf[j] = *(const bf16x8*)&lB[(wn + j*16 + lm)*32 + qd*8];
    #pragma unroll
    for (int i = 0; i < 4; i++)
      #pragma unroll
      for (int j = 0; j < 4; j++)
        acc[i][j] = __builtin_amdgcn_mfma_f32_16x16x32_bf16(af[i], bf[j], acc[i][j], 0, 0, 0);
    __syncthreads();
  }

  // C/D layout: col = lane&15, row = (lane>>4)*4 + reg   [verified m89/m91]
  const int row0 = by*128 + wm + qd*4;
  const int col0 = bx*128 + wn + lm;
  ushort_t* Cb = (ushort_t*)Cv + (size_t)bz * sC;
  float*    Cf = (float*)Cv    + (size_t)bz * sC;
  #pragma unroll
  for (int j = 0; j < 4; j++){
    int col = col0 + j*16;
    float bv = hasBias ? bias[col] : 0.f;
    #pragma unroll
    for (int i = 0; i < 4; i++)
      #pragma unroll
      for (int r = 0; r < 4; r++){
        size_t idx = (size_t)(row0 + i*16 + r) * N + col;
        float v = acc[i][j][r] + bv;
        if (outBF16) Cb[idx] = f2b(v); else Cf[idx] = v;
      }
  }
}

// ==================== 256x128-tile, BK=64, counted-vmcnt GEMM, 4Mx2N waves ====================
// R10 change (single variable): MERGE the two k-slot phases — issue all 16 ds_reads +
// 6 stage loads, ONE lgkmcnt(0), then an uninterrupted 32-MFMA burst. Halves lgkm
// stalls per tile; longer MFMA bursts cover the other resident wave's read phase.
// global_load_lds only increments vmcnt, so lgkmcnt(0) waits exactly on our ds_reads.
// Tile-boundary vmcnt+BAR buffer guard unchanged (verified R8/R9).
#define G2_STAGE_A(sel) do{ \
    ushort_t* _d = &lA3[(sel)*(256*64) + (w*8)*64]; \
    CP16(gA0, _d); \
    CP16(gA1, _d + 64*64); \
    CP16(gA2, _d + 128*64); \
    CP16(gA3, _d + 192*64); }while(0)
#define G2_STAGE_B(sel) do{ \
    ushort_t* _d = &lB3[(sel)*(128*64) + (w*8)*64]; \
    CP16(gB0, _d); \
    CP16(gB1, _d + 64*64); }while(0)
#define G2_ADV() do{ gA0+=64; gA1+=64; gA2+=64; gA3+=64; gB0+=64; gB1+=64; }while(0)
#define BAR()    asm volatile("s_barrier" ::: "memory")
#define LGKM0()  do{ asm volatile("s_waitcnt lgkmcnt(0)" ::: "memory"); \
                     __builtin_amdgcn_sched_barrier(0); }while(0)

__global__ __launch_bounds__(512, 2) void gemm256_kernel(
    const ushort_t* __restrict__ A, const ushort_t* __restrict__ Bm,
    ushort_t* __restrict__ C,
    int M, int N, int K, int lda, int ldb,
    long long sA, long long sB, long long sC, int gx, int gxy)
{
  __shared__ ushort_t lA3[3 * 256 * 64];   // 96 KB
  __shared__ ushort_t lB3[3 * 128 * 64];   // 48 KB
  (void)M;

  const int bpx = gridDim.x >> 3;
  const int lin = blockIdx.x;
  const int glob = (lin & 7) * bpx + (lin >> 3);   // XCD-chunked (grid % 8 == 0)
  const int bz = glob / gxy;
  const int rem = glob - bz * gxy;
  const int by = rem / gx;
  const int bx = rem - by * gx;

  A  += (size_t)bz * sA;
  Bm += (size_t)bz * sB;

  const int tid = threadIdx.x;
  const int w = tid >> 6, l = tid & 63;
  const int lm = l & 15, qd = l >> 4;
  const int wm = w & 3, wn = w >> 2;     // 4M x 2N wave grid

  const int srow = l >> 3;
  const int sch  = (l & 7) ^ srow;

  const ushort_t* gA0 = A + (size_t)(by*256 +       w*8 + srow) * lda + sch*8;
  const ushort_t* gA1 = gA0 + (size_t)64  * lda;
  const ushort_t* gA2 = gA0 + (size_t)128 * lda;
  const ushort_t* gA3 = gA0 + (size_t)192 * lda;
  const ushort_t* gB0 = Bm + (size_t)(bx*128 +      w*8 + srow) * ldb + sch*8;
  const ushort_t* gB1 = gB0 + (size_t)64  * ldb;

  f32x4 acc[4][4];
  #pragma unroll
  for (int i = 0; i < 4; i++)
    #pragma unroll
    for (int j = 0; j < 4; j++) acc[i][j] = (f32x4){0.f,0.f,0.f,0.f};

  // prologue: stage tiles 0 and 1 (A0[4],B0[2],A1[4],B1[2] = 12 loads)
  G2_STAGE_A(0); G2_STAGE_B(0); G2_ADV();
  G2_STAGE_A(1); G2_STAGE_B(1); G2_ADV();
  asm volatile("s_waitcnt vmcnt(6)" ::: "memory");   // tile 0 landed; tile 1 in flight
  BAR();

  const int NT = K >> 6;
  int rd = 0, st = 2;
  #pragma unroll 1
  for (int t = 0; t < NT; ++t){
    const ushort_t* sa = &lA3[rd*(256*64) + (wm*64)*64];
    const ushort_t* sb = &lB3[rd*(128*64) + (wn*64)*64];
    const bool pre = (t + 2 < NT);

    // -------- merged tile body: 16 ds_reads + stage, 1 wait, 32 MFMA --------
    const int ch0 = qd ^ (lm & 7);
    const int ch1 = (4 | qd) ^ (lm & 7);
    bf16x8 af0[4], bf0[4], af1[4], bf1[4];
    #pragma unroll
    for (int i = 0; i < 4; i++) af0[i] = *(const bf16x8*)&sa[(i*16 + lm)*64 + ch0*8];
    #pragma unroll
    for (int j = 0; j < 4; j++) bf0[j] = *(const bf16x8*)&sb[(j*16 + lm)*64 + ch0*8];
    #pragma unroll
    for (int i = 0; i < 4; i++) af1[i] = *(const bf16x8*)&sa[(i*16 + lm)*64 + ch1*8];
    #pragma unroll
    for (int j = 0; j < 4; j++) bf1[j] = *(const bf16x8*)&sb[(j*16 + lm)*64 + ch1*8];
    if (pre){ G2_STAGE_A(st); G2_STAGE_B(st); G2_ADV(); }
    LGKM0();
    __builtin_amdgcn_s_setprio(1);
    #pragma unroll
    for (int i = 0; i < 4; i++)
      #pragma unroll
      for (int j = 0; j < 4; j++)
        acc[i][j] = __builtin_amdgcn_mfma_f32_16x16x32_bf16(af0[i], bf0[j], acc[i][j], 0, 0, 0);
    #pragma unroll
    for (int i = 0; i < 4; i++)
      #pragma unroll
      for (int j = 0; j < 4; j++)
        acc[i][j] = __builtin_amdgcn_mfma_f32_16x16x32_bf16(af1[i], bf1[j], acc[i][j], 0, 0, 0);
    __builtin_amdgcn_s_setprio(0);

    if (t < NT - 1){
      // ONE sync point per K-tile: tile t+1 resident, all reads of buffer st retired.
      if (pre) asm volatile("s_waitcnt vmcnt(6)" ::: "memory");
      else     asm volatile("s_waitcnt vmcnt(0)" ::: "memory");
      BAR();
    }
    rd = (rd == 2) ? 0 : rd + 1;
    st = (st == 2) ? 0 : st + 1;
  }

  // C/D layout: col = lane&15, row = (lane>>4)*4 + reg   [verified m89/m91]
  const int row0 = by*256 + wm*64 + qd*4;
  const int col0 = bx*128 + wn*64 + lm;
  ushort_t* Cp = C + (size_t)bz * sC;
  #pragma unroll
  for (int j = 0; j < 4; j++)
    #pragma unroll
    for (int i = 0; i < 4; i++)
      #pragma unroll
      for (int r = 0; r < 4; r++)
        Cp[(size_t)(row0 + i*16 + r) * N + col0 + j*16] = f2b(acc[i][j][r]);
}

// ----- banded l_att stencil on km: qm2[t] = sum_s w[t,s]*km[b,s]; gates from kw -----
__global__ __launch_bounds__(256) void band_kernel(
    const ushort_t* __restrict__ kmb, const float* __restrict__ mask_src,
    const float* __restrict__ steps, const float* __restrict__ kw,
    const float* __restrict__ bg, ushort_t* __restrict__ qm2b,
    float* __restrict__ gates)
{
  __shared__ float shw[8][17];
  __shared__ int shslo[8];
  int bx0 = blockIdx.x;
  int bx = (bx0 & 7) * 128 + (bx0 >> 3);   // bijective: b = bx0&7 stays on its XCD
  int b = bx >> 7, t0 = (bx & 127) * 8;
  int tid = threadIdx.x;

  if (tid < 8){
    int t = t0 + tid;
    float c = steps[b] * (float)t;
    int slo = (int)ceilf(c - 8.0f);
    float w[17], m = -3e38f;
    #pragma unroll
    for (int i = 0; i < 17; i++){
      int s = slo + i;
      float l = -3e38f;
      if (s >= 0 && s < SS){
        float dd = (float)s - c;
        l = -dd*dd*(1.0f/0.3f) - INF_*(1.0f - mask_src[b*SS + s]);
      }
      w[i] = l; m = fmaxf(m, l);
    }
    float norm = 0.f, ga = 0.f;
    #pragma unroll
    for (int i = 0; i < 17; i++){
      float e = __expf(w[i] - m);
      int s = slo + i;
      if (s >= 0 && s < SS) ga += e * kw[b*SS + s]; else e = 0.f;
      w[i] = e; norm += e;
    }
    float inv = 1.0f / norm;
    #pragma unroll
    for (int i = 0; i < 17; i++) shw[tid][i] = w[i] * inv;
    shslo[tid] = slo;
    gates[b*TT + t] = 1.0f / (1.0f + __expf(-(ga*inv + bg[0])));
  }
  __syncthreads();

  int smin = shslo[0], smax = shslo[7] + 16;
  if (smin < 0) smin = 0;
  if (smax > SS-1) smax = SS-1;
  int d0 = tid * 4;
  float acc[8][4];
  #pragma unroll
  for (int t = 0; t < 8; t++){ acc[t][0]=0.f; acc[t][1]=0.f; acc[t][2]=0.f; acc[t][3]=0.f; }

  const ushort_t* kbase = kmb + ((size_t)b*SS)*DD + d0;
  for (int s = smin; s <= smax; s++){
    ushort4 kv = *(const ushort4*)(kbase + (size_t)s*DD);
    float k0 = b2f(kv.x), k1 = b2f(kv.y), k2 = b2f(kv.z), k3 = b2f(kv.w);
    #pragma unroll
    for (int t = 0; t < 8; t++){
      unsigned u = (unsigned)(s - shslo[t]);
      if (u < 17u){
        float wgt = shw[t][u];
        acc[t][0] += wgt*k0; acc[t][1] += wgt*k1; acc[t][2] += wgt*k2; acc[t][3] += wgt*k3;
      }
    }
  }
  #pragma unroll
  for (int t = 0; t < 8; t++){
    ushort4 o; o.x=f2b(acc[t][0]); o.y=f2b(acc[t][1]); o.z=f2b(acc[t][2]); o.w=f2b(acc[t][3]);
    *(ushort4*)(qm2b + ((size_t)(b*TT + t0 + t))*DD + d0) = o;
  }
}

// ------- wave-per-row softmax+mix (no LDS, no barriers). 4 rows/block, 2048 blocks.
__global__ __launch_bounds__(256) void softmax_mix_kernel(
    const ushort_t* __restrict__ dotsb, float* __restrict__ out,
    const float* __restrict__ mask_src, const float* __restrict__ steps,
    const float* __restrict__ gates, const float* __restrict__ cv)
{
  int blk0 = blockIdx.x;                 // 0..2047
  int tid = threadIdx.x, wv = tid >> 6, l = tid & 63;
  int b = blk0 & 7;
  int t = (blk0 >> 3)*4 + wv;
  int row = b*TT + t;
  float c = steps[b] * (float)t;
  float g = gates[row];

  const ushort_t* dp = dotsb + (size_t)row*SS;
  const float* mp = mask_src + (size_t)b*SS;
  const float* cp = cv + (size_t)b*SS;

  float dl[16], ll[16];
  float dmax = -3e38f, lmax = -3e38f;
  #pragma unroll
  for (int i = 0; i < 4; i++){
    int s0 = i*256 + l*4;                // coalesced across the wave
    ushort4 dv = *(const ushort4*)(dp + s0);
    float4 mv = *(const float4*)(mp + s0);
    float4 cva = *(const float4*)(cp + s0);
    float dvf[4] = {b2f(dv.x)+cva.x, b2f(dv.y)+cva.y, b2f(dv.z)+cva.z, b2f(dv.w)+cva.w};
    float msk[4] = {mv.x, mv.y, mv.z, mv.w};
    #pragma unroll
    for (int r = 0; r < 4; r++){
      float im = INF_ * (1.0f - msk[r]);
      dl[i*4+r] = (dvf[r] - im) * (1.0f/32.0f);
      float dd = (float)(s0 + r) - c;
      ll[i*4+r] = -dd*dd*(1.0f/0.3f) - im;
      dmax = fmaxf(dmax, dl[i*4+r]);
      lmax = fmaxf(lmax, ll[i*4+r]);
    }
  }
  #pragma unroll
  for (int o = 32; o; o >>= 1){
    dmax = fmaxf(dmax, __shfl_xor(dmax, o));
    lmax = fmaxf(lmax, __shfl_xor(lmax, o));
  }
  float psum = 0.f, lsum = 0.f;
  #pragma unroll
  for (int j = 0; j < 16; j++){
    dl[j] = __expf(dl[j] - dmax); psum += dl[j];
    ll[j] = __expf(ll[j] - lmax); lsum += ll[j];
  }
  #pragma unroll
  for (int o = 32; o; o >>= 1){
    psum += __shfl_xor(psum, o);
    lsum += __shfl_xor(lsum, o);
  }
  float ip = (1.0f - g) / psum, il = g / lsum;
  #pragma unroll
  for (int i = 0; i < 4; i++){
    int s0 = i*256 + l*4;
    float4 ov;
    ov.x = dl[i*4+0]*ip + ll[i*4+0]*il;
    ov.y = dl[i*4+1]*ip + ll[i*4+1]*il;
    ov.z = dl[i*4+2]*ip + ll[i*4+2]*il;
    ov.w = dl[i*4+3]*ip + ll[i*4+3]*il;
    *(float4*)(out + (size_t)row*SS + s0) = ov;
  }
}

extern "C" void kernel_launch(void* const* d_in, const int* in_sizes, int n_in,
                              void* d_out, int out_size, void* d_ws, size_t ws_size,
                              hipStream_t stream)
{
  const float* key      = (const float*)d_in[0];
  const float* mask_src = (const float*)d_in[1];
  const float* mask_trg = (const float*)d_in[2];
  const float* Wq       = (const float*)d_in[3];
  const float* bq       = (const float*)d_in[4];
  const float* Wk       = (const float*)d_in[5];
  const float* bk       = (const float*)d_in[6];
  const float* wg       = (const float*)d_in[7];
  const float* bg       = (const float*)d_in[8];
  float* out = (float*)d_out;   // fp32 [B,T,S] = 32 MB, written ONLY by softmax
  (void)bk;  // bk contributes only a row-constant softmax shift -> cancels

  // ws layout (~54.3 MB):
  char* ws = (char*)d_ws;
  float* steps     = (float*)ws;                         // 32 B
  float* gates     = (float*)(ws + 4096);                // 32 KB
  float* cv        = (float*)(ws + 4096 + 32768);        // 32 KB
  float* kw        = (float*)(ws + 4096 + 65536);        // 32 KB
  float* v2        = (float*)(ws + 4096 + 98304);        // 4 KB
  ushort_t* WqTb   = (ushort_t*)(ws + 131072);           // 2 MB
  ushort_t* WkTb   = WqTb + (size_t)DD*DD;               // 2 MB
  ushort_t* WmTb   = WkTb + (size_t)DD*DD;               // 2 MB
  ushort_t* keyb   = WmTb + (size_t)DD*DD;               // 16 MB
  ushort_t* kmb    = keyb + (size_t)BB*SS*DD;            // 16 MB (km; DEAD after band -> reused as dotsb)
  char* shared16   = (char*)(kmb + (size_t)BB*SS*DD);    // 16 MB: WmT partials, later qm2b
  float* wmPart    = (float*)shared16;                   // 4 x 1M fp32
  ushort_t* qm2b   = (ushort_t*)shared16;                // 16 MB (after the fused reduce)
  ushort_t* dotsb  = kmb;                                // bf16 dots in km's dead slot

  // 1) transposes + steps + v2 (64-block, atomic-free)
  pre_kernel<<<2120, 256, 0, stream>>>(Wq, Wk, WqTb, WkTb, mask_src, mask_trg, steps, v2, bq);
  // 2) WmT[f,e] = sum_d Wk[d,f] Wq[d,e] = WkT @ WqT^T, split-K=4 over d -> fp32 partials
  gemm_bt_kernel<<<256, 256, 0, stream>>>(
      WkTb, WqTb, nullptr, (void*)wmPart, DD, DD, DD/4, DD, DD,
      DD/4, DD/4, (long long)DD*DD, 0, 0, 8, 64);
  // 3) key convert (wave-per-row) + folded WmT partial reduce (blocks >= 2048)
  key_convert_kernel<<<2048 + 256, 256, 0, stream>>>(
      key, wg, v2, keyb, kw, cv, wmPart, WmTb);
  // 4) km = keyb @ Wm   [8192 x 1024 x 1024] -> bf16
  gemm256_kernel<<<256, 512, 0, stream>>>(
      keyb, WmTb, kmb, BB*SS, DD, DD, DD, DD, 0, 0, 0, 8, 256);
  // 5) qm2 = l_att · km (banded) + gates  (XCD-affine)
  band_kernel<<<BB*TT/8, 256, 0, stream>>>(kmb, mask_src, steps, kw, bg, qm2b, gates);
  // 6) dots[b] = qm2[b] @ keyb[b]^T -> dotsb (one batch per XCD)
  gemm256_kernel<<<256, 512, 0, stream>>>(
      qm2b, keyb, dotsb, TT, SS, DD, DD, DD,
      (long long)TT*DD, (long long)SS*DD, (long long)TT*SS, 8, 32);
  // 7) softmax + exact l_att + gated mix (wave-per-row, XCD-affine)
  softmax_mix_kernel<<<2048, 256, 0, stream>>>(dotsb, out, mask_src, steps, gates, cv);
}